// Round 1
// baseline (379.921 us; speedup 1.0000x reference)
//
#include <hip/hip_runtime.h>
#include <hip/hip_bf16.h>
#include <cstdint>
#include <cstddef>

#define EPS 1e-5f
#define NEG 0.2f

static constexpr int B_ = 8, N_ = 4096, K_ = 20, M_ = B_ * N_;  // M = 32768

// ---------------- BN param folding: inv = g*rsqrt(v+eps), beta = b - m*inv ----
__global__ void setup_params(
    const float* __restrict__ g1, const float* __restrict__ b1, const float* __restrict__ m1, const float* __restrict__ v1,
    const float* __restrict__ g2, const float* __restrict__ b2, const float* __restrict__ m2, const float* __restrict__ v2,
    const float* __restrict__ g3, const float* __restrict__ b3, const float* __restrict__ m3, const float* __restrict__ v3,
    const float* __restrict__ g4, const float* __restrict__ b4, const float* __restrict__ m4, const float* __restrict__ v4,
    const float* __restrict__ g5, const float* __restrict__ b5, const float* __restrict__ m5, const float* __restrict__ v5,
    const float* __restrict__ g6, const float* __restrict__ b6, const float* __restrict__ m6, const float* __restrict__ v6,
    float* __restrict__ P) {
  const float* G[6]  = {g1, g2, g3, g4, g5, g6};
  const float* Bb[6] = {b1, b2, b3, b4, b5, b6};
  const float* Mm[6] = {m1, m2, m3, m4, m5, m6};
  const float* Vv[6] = {v1, v2, v3, v4, v5, v6};
  const int Cs[6] = {64, 64, 128, 256, 256, 128};
  const int OI[6] = {0, 128, 256, 512, 1024, 1536};   // inv offsets
  const int OB[6] = {64, 192, 384, 768, 1280, 1664};  // beta offsets
  for (int l = 0; l < 6; ++l) {
    for (int c = threadIdx.x; c < Cs[l]; c += blockDim.x) {
      float iv = G[l][c] * rsqrtf(Vv[l][c] + EPS);
      P[OI[l] + c] = iv;
      P[OB[l] + c] = Bb[l][c] - Mm[l][c] * iv;
    }
  }
}

// ---------------- layer-1 GEMM, C=3 special case ----------------------------
// z[p,o] = (x[b,0,n]*w[o,0] + x[b,1,n]*w[o,1] + x[b,2,n]*w[o,2]) * inv[o]
__global__ __launch_bounds__(256) void gemm_c3(
    const float* __restrict__ x,   // (B, 3, N)
    const float* __restrict__ w,   // (64, 3)
    const float* __restrict__ inv,
    float* __restrict__ z) {       // (M, 64)
  const int o  = threadIdx.x & 63;
  const int pi = threadIdx.x >> 6;
  const float w0 = w[o * 3 + 0], w1 = w[o * 3 + 1], w2 = w[o * 3 + 2];
  const float iv = inv[o];
  const int pbase = blockIdx.x * 64;
  const int b = pbase >> 12;
  const int nbase = pbase & (N_ - 1);
  const float* xb = x + (size_t)b * 3 * N_;
  for (int pj = pi; pj < 64; pj += 4) {
    const int n = nbase + pj;
    const float x0 = xb[n], x1 = xb[N_ + n], x2 = xb[2 * N_ + n];
    z[(size_t)(pbase + pj) * 64 + o] = (x0 * w0 + x1 * w1 + x2 * w2) * iv;
  }
}

// ---------------- generic fp32 tiled GEMM ------------------------------------
// out[m, o] = f( sum_c A[m, c] * W[o, c] )
// MODE 0: out = acc*inv[o]               (edgeconv pre-pass)
// MODE 1: t = acc*inv[o]+beta[o]; out = max(t, 0.2t)   (pointconv)
template <int BM, int BO, int TM, int TO, int MODE>
__global__ __launch_bounds__(256) void gemm_f32(
    const float* __restrict__ A, int lda,
    const float* __restrict__ W,  // (O, C) row-major
    const float* __restrict__ inv, const float* __restrict__ betap,
    float* __restrict__ out, int ldout, int C) {
  constexpr int BK = 16;
  __shared__ alignas(16) float As[BK][BM];
  __shared__ alignas(16) float Ws[BK][BO];
  const int tid = threadIdx.x;
  const int bm = blockIdx.x * BM;
  const int bo = blockIdx.y * BO;
  const int ty = tid >> 4, tx = tid & 15;  // 16x16 thread grid

  float acc[TM][TO];
#pragma unroll
  for (int i = 0; i < TM; ++i)
#pragma unroll
    for (int j = 0; j < TO; ++j) acc[i][j] = 0.f;

  constexpr int A_F4 = BM * BK / (256 * 4);
  constexpr int W_F4 = BO * BK / (256 * 4);
  static_assert(A_F4 >= 1 && W_F4 >= 1, "tile too small");

  for (int k0 = 0; k0 < C; k0 += BK) {
#pragma unroll
    for (int q = 0; q < A_F4; ++q) {
      const int lin = tid + q * 256;
      const int row = lin >> 2, cq = lin & 3;
      const float4 v = *reinterpret_cast<const float4*>(A + (size_t)(bm + row) * lda + k0 + cq * 4);
      As[cq * 4 + 0][row] = v.x; As[cq * 4 + 1][row] = v.y;
      As[cq * 4 + 2][row] = v.z; As[cq * 4 + 3][row] = v.w;
    }
#pragma unroll
    for (int q = 0; q < W_F4; ++q) {
      const int lin = tid + q * 256;
      const int row = lin >> 2, cq = lin & 3;
      const float4 v = *reinterpret_cast<const float4*>(W + (size_t)(bo + row) * C + k0 + cq * 4);
      Ws[cq * 4 + 0][row] = v.x; Ws[cq * 4 + 1][row] = v.y;
      Ws[cq * 4 + 2][row] = v.z; Ws[cq * 4 + 3][row] = v.w;
    }
    __syncthreads();
#pragma unroll
    for (int k = 0; k < BK; ++k) {
      float a[TM], wv[TO];
#pragma unroll
      for (int i = 0; i < TM; i += 4) {
        const float4 t = *reinterpret_cast<const float4*>(&As[k][ty * TM + i]);
        a[i] = t.x; a[i + 1] = t.y; a[i + 2] = t.z; a[i + 3] = t.w;
      }
#pragma unroll
      for (int j = 0; j < TO; j += 4) {
        const float4 t = *reinterpret_cast<const float4*>(&Ws[k][tx * TO + j]);
        wv[j] = t.x; wv[j + 1] = t.y; wv[j + 2] = t.z; wv[j + 3] = t.w;
      }
#pragma unroll
      for (int i = 0; i < TM; ++i)
#pragma unroll
        for (int j = 0; j < TO; ++j) acc[i][j] = fmaf(a[i], wv[j], acc[i][j]);
    }
    __syncthreads();
  }

  float iv[TO], bt[TO];
#pragma unroll
  for (int j = 0; j < TO; ++j) {
    const int o = bo + tx * TO + j;
    iv[j] = inv[o];
    bt[j] = (MODE == 1) ? betap[o] : 0.f;
  }
#pragma unroll
  for (int i = 0; i < TM; ++i) {
    const int r = bm + ty * TM + i;
#pragma unroll
    for (int j0 = 0; j0 < TO; j0 += 4) {
      float4 v;
      float t0 = acc[i][j0 + 0] * iv[j0 + 0];
      float t1 = acc[i][j0 + 1] * iv[j0 + 1];
      float t2 = acc[i][j0 + 2] * iv[j0 + 2];
      float t3 = acc[i][j0 + 3] * iv[j0 + 3];
      if (MODE == 1) {
        t0 += bt[j0 + 0]; t1 += bt[j0 + 1]; t2 += bt[j0 + 2]; t3 += bt[j0 + 3];
        t0 = fmaxf(t0, NEG * t0); t1 = fmaxf(t1, NEG * t1);
        t2 = fmaxf(t2, NEG * t2); t3 = fmaxf(t3, NEG * t3);
      }
      v.x = t0; v.y = t1; v.z = t2; v.w = t3;
      *reinterpret_cast<float4*>(out + (size_t)r * ldout + bo + tx * TO + j0) = v;
    }
  }
}

// ---------------- edge max: out[p,o] = max_k lrelu(z[nbr,o]-z[p,o]+beta[o]) --
template <int R>  // O = 64*R
__global__ __launch_bounds__(256) void edge_max(
    const float* __restrict__ z, const int* __restrict__ idx,
    const float* __restrict__ betap, float* __restrict__ out, int ldout) {
  constexpr int O = R * 64;
  const int lane = threadIdx.x & 63;
  const int p = (blockIdx.x << 2) + (threadIdx.x >> 6);
  const int b = p >> 12;
  const int* ip = idx + (size_t)p * K_;
  const float* zc = z + (size_t)p * O;
  float c[R], bt[R], mx[R];
#pragma unroll
  for (int r = 0; r < R; ++r) {
    c[r] = zc[lane + 64 * r];
    bt[r] = betap[lane + 64 * r];
    mx[r] = -1e30f;
  }
  const float* zb = z + ((size_t)(b << 12)) * O;
#pragma unroll 4
  for (int k = 0; k < K_; ++k) {
    const int g = ip[k];
    const float* zn = zb + (size_t)g * O;
#pragma unroll
    for (int r = 0; r < R; ++r) {
      const float e = zn[lane + 64 * r] - c[r] + bt[r];
      const float v = fmaxf(e, NEG * e);   // lrelu(e) = max(e, 0.2e)
      mx[r] = fmaxf(mx[r], v);
    }
  }
  float* op = out + (size_t)p * ldout;
#pragma unroll
  for (int r = 0; r < R; ++r) op[lane + 64 * r] = mx[r];
}

// ---------------- final 128 -> 1 projection + lrelu --------------------------
__global__ __launch_bounds__(256) void final_dot(
    const float* __restrict__ h,   // (M, 128)
    const float* __restrict__ w7,  // (1, 128)
    float* __restrict__ out) {     // (M)
  const int lane = threadIdx.x & 63;
  const int p = (blockIdx.x << 2) + (threadIdx.x >> 6);
  const float* hp = h + (size_t)p * 128;
  float s = hp[lane] * w7[lane] + hp[64 + lane] * w7[64 + lane];
#pragma unroll
  for (int off = 32; off; off >>= 1) s += __shfl_down(s, off, 64);
  if (lane == 0) out[p] = fmaxf(s, NEG * s);
}

// ---------------- launch -----------------------------------------------------
extern "C" void kernel_launch(void* const* d_in, const int* in_sizes, int n_in,
                              void* d_out, int out_size, void* d_ws, size_t ws_size,
                              hipStream_t stream) {
  const float* x  = (const float*)d_in[0];
  const int* idx  = (const int*)d_in[1];
  const float* w[7];
  for (int i = 0; i < 7; ++i) w[i] = (const float*)d_in[2 + i];
  const float* bn[24];
  for (int i = 0; i < 24; ++i) bn[i] = (const float*)d_in[9 + i];

  // workspace map:  P (32 KB) | z (32 MB) | h512 (64 MB).  h5 aliases z, h6 aliases h512.
  float* P    = (float*)d_ws;
  float* z    = (float*)((char*)d_ws + (32 << 10));
  float* h512 = (float*)((char*)d_ws + (32 << 10) + ((size_t)32 << 20));
  float* h5 = z;
  float* h6 = h512;

  setup_params<<<1, 256, 0, stream>>>(
      bn[0], bn[1], bn[2], bn[3],   bn[4], bn[5], bn[6], bn[7],
      bn[8], bn[9], bn[10], bn[11], bn[12], bn[13], bn[14], bn[15],
      bn[16], bn[17], bn[18], bn[19], bn[20], bn[21], bn[22], bn[23], P);

  const float* inv1 = P + 0,    *bt1 = P + 64;
  const float* inv2 = P + 128,  *bt2 = P + 192;
  const float* inv3 = P + 256,  *bt3 = P + 384;
  const float* inv4 = P + 512,  *bt4 = P + 768;
  const float* inv5 = P + 1024, *bt5 = P + 1280;
  const float* inv6 = P + 1536, *bt6 = P + 1664;

  // L1: edgeconv(3 -> 64)
  gemm_c3<<<M_ / 64, 256, 0, stream>>>(x, w[0], inv1, z);
  edge_max<1><<<M_ / 4, 256, 0, stream>>>(z, idx, bt1, h512 + 0, 512);
  // L2: edgeconv(64 -> 64)
  gemm_f32<64, 64, 4, 4, 0><<<dim3(M_ / 64, 1), 256, 0, stream>>>(
      h512 + 0, 512, w[1], inv2, nullptr, z, 64, 64);
  edge_max<1><<<M_ / 4, 256, 0, stream>>>(z, idx, bt2, h512 + 64, 512);
  // L3: edgeconv(64 -> 128)
  gemm_f32<128, 128, 8, 8, 0><<<dim3(M_ / 128, 1), 256, 0, stream>>>(
      h512 + 64, 512, w[2], inv3, nullptr, z, 128, 64);
  edge_max<2><<<M_ / 4, 256, 0, stream>>>(z, idx, bt3, h512 + 128, 512);
  // L4: edgeconv(128 -> 256)
  gemm_f32<128, 128, 8, 8, 0><<<dim3(M_ / 128, 2), 256, 0, stream>>>(
      h512 + 128, 512, w[3], inv4, nullptr, z, 256, 128);
  edge_max<4><<<M_ / 4, 256, 0, stream>>>(z, idx, bt4, h512 + 256, 512);
  // L5: pointconv(512 -> 256)
  gemm_f32<128, 128, 8, 8, 1><<<dim3(M_ / 128, 2), 256, 0, stream>>>(
      h512, 512, w[4], inv5, bt5, h5, 256, 512);
  // L6: pointconv(256 -> 128)
  gemm_f32<128, 128, 8, 8, 1><<<dim3(M_ / 128, 1), 256, 0, stream>>>(
      h5, 256, w[5], inv6, bt6, h6, 128, 256);
  // L7: final 128 -> 1 + lrelu
  final_dot<<<M_ / 4, 256, 0, stream>>>(h6, w[6], (float*)d_out);
}

// Round 3
// 192.447 us; speedup vs baseline: 1.9742x; 1.9742x over previous
//
#include <hip/hip_runtime.h>
#include <hip/hip_bf16.h>
#include <cstdint>
#include <cstddef>

#define EPS 1e-5f
#define NEG 0.2f

static constexpr int B_ = 8, N_ = 4096, K_ = 20, M_ = B_ * N_;  // M = 32768

typedef __attribute__((ext_vector_type(8))) _Float16 f16x8;
typedef __attribute__((ext_vector_type(4))) _Float16 f16x4;
typedef __attribute__((ext_vector_type(2))) _Float16 f16x2;
typedef __attribute__((ext_vector_type(4))) float f32x4;

template <int CPT> struct VecT;
template <> struct VecT<2> { using T = f16x2; };
template <> struct VecT<4> { using T = f16x4; };

// ---------------- BN param folding: inv = g*rsqrt(v+eps), beta = b - m*inv ----
__global__ void setup_params(
    const float* __restrict__ g1, const float* __restrict__ b1, const float* __restrict__ m1, const float* __restrict__ v1,
    const float* __restrict__ g2, const float* __restrict__ b2, const float* __restrict__ m2, const float* __restrict__ v2,
    const float* __restrict__ g3, const float* __restrict__ b3, const float* __restrict__ m3, const float* __restrict__ v3,
    const float* __restrict__ g4, const float* __restrict__ b4, const float* __restrict__ m4, const float* __restrict__ v4,
    const float* __restrict__ g5, const float* __restrict__ b5, const float* __restrict__ m5, const float* __restrict__ v5,
    const float* __restrict__ g6, const float* __restrict__ b6, const float* __restrict__ m6, const float* __restrict__ v6,
    float* __restrict__ P) {
  const float* G[6]  = {g1, g2, g3, g4, g5, g6};
  const float* Bb[6] = {b1, b2, b3, b4, b5, b6};
  const float* Mm[6] = {m1, m2, m3, m4, m5, m6};
  const float* Vv[6] = {v1, v2, v3, v4, v5, v6};
  const int Cs[6] = {64, 64, 128, 256, 256, 128};
  const int OI[6] = {0, 128, 256, 512, 1024, 1536};   // inv offsets
  const int OB[6] = {64, 192, 384, 768, 1280, 1664};  // beta offsets
  for (int l = 0; l < 6; ++l) {
    for (int c = threadIdx.x; c < Cs[l]; c += blockDim.x) {
      float iv = G[l][c] * rsqrtf(Vv[l][c] + EPS);
      P[OI[l] + c] = iv;
      P[OB[l] + c] = Bb[l][c] - Mm[l][c] * iv;
    }
  }
}

// ---------------- weight conversion: Wh[o][c] = f16(w[o][c] * inv[o]) --------
// segments: w2 [0,4096) 16 blks | w3 [4096,12288) 32 | w4 [12288,45056) 128 |
//           w5 [45056,176128) 512 | w6 [176128,208896) 128   (816 blocks total)
__global__ __launch_bounds__(256) void convert_all(
    const float* __restrict__ w2, const float* __restrict__ w3,
    const float* __restrict__ w4, const float* __restrict__ w5,
    const float* __restrict__ w6, const float* __restrict__ P,
    _Float16* __restrict__ Wh) {
  const int bid = blockIdx.x, tid = threadIdx.x;
  const float* w; const float* inv; _Float16* dst; int lc, base;
  if (bid < 16)       { w = w2; inv = P + 128;  dst = Wh + 0;      lc = 6; base = 0;   }
  else if (bid < 48)  { w = w3; inv = P + 256;  dst = Wh + 4096;   lc = 6; base = 16;  }
  else if (bid < 176) { w = w4; inv = P + 512;  dst = Wh + 12288;  lc = 7; base = 48;  }
  else if (bid < 688) { w = w5; inv = P + 1024; dst = Wh + 45056;  lc = 9; base = 176; }
  else                { w = w6; inv = P + 1536; dst = Wh + 176128; lc = 8; base = 688; }
  const int e = (bid - base) * 256 + tid;
  dst[e] = (_Float16)(w[e] * inv[e >> lc]);
}

// ---------------- layer-1 GEMM, C=3 special case -----------------------------
__global__ __launch_bounds__(256) void gemm_c3(
    const float* __restrict__ x,   // (B, 3, N)
    const float* __restrict__ w,   // (64, 3)
    const float* __restrict__ inv,
    _Float16* __restrict__ z) {    // (M, 64) fp16
  const int o  = threadIdx.x & 63;
  const int pi = threadIdx.x >> 6;
  const float w0 = w[o * 3 + 0], w1 = w[o * 3 + 1], w2 = w[o * 3 + 2];
  const float iv = inv[o];
  const int pbase = blockIdx.x * 64;
  const int b = pbase >> 12;
  const int nbase = pbase & (N_ - 1);
  const float* xb = x + (size_t)b * 3 * N_;
  for (int pj = pi; pj < 64; pj += 4) {
    const int n = nbase + pj;
    const float x0 = xb[n], x1 = xb[N_ + n], x2 = xb[2 * N_ + n];
    z[(size_t)(pbase + pj) * 64 + o] = (_Float16)((x0 * w0 + x1 * w1 + x2 * w2) * iv);
  }
}

// ---------------- fp16 MFMA GEMM, no LDS -------------------------------------
// out[m,o] = f( sum_c A[m,c] * W[o,c] )   (inv pre-folded into W)
// MODE 0: out = acc            MODE 1: t = acc + beta[o]; out = max(t, 0.2t)
// block: 256 thr = 4 waves (2x2), tile 128x64, per-wave 64x32.
template <int MODE, int C>
__global__ __launch_bounds__(256) void gemm_mfma(
    const _Float16* __restrict__ A, int lda,
    const _Float16* __restrict__ W,       // (O, C) fp16, inv-folded
    const float* __restrict__ betap,
    _Float16* __restrict__ out, int ldout) {
  const int lane = threadIdx.x & 63;
  const int wid  = threadIdx.x >> 6;
  const int wr = wid >> 1, wc = wid & 1;
  const int m0 = blockIdx.x * 128 + wr * 64;
  const int o0 = blockIdx.y * 64 + wc * 32;
  const int lr = lane & 15, lk = lane >> 4;
  const _Float16* Ap = A + (size_t)(m0 + lr) * lda + lk * 8;
  const _Float16* Wp = W + (size_t)(o0 + lr) * C + lk * 8;

  f32x4 acc[4][2];
#pragma unroll
  for (int i = 0; i < 4; ++i)
#pragma unroll
    for (int j = 0; j < 2; ++j) acc[i][j] = (f32x4){0.f, 0.f, 0.f, 0.f};

#pragma unroll
  for (int k0 = 0; k0 < C; k0 += 32) {
    const f16x8 b0 = *reinterpret_cast<const f16x8*>(Wp + k0);
    const f16x8 b1 = *reinterpret_cast<const f16x8*>(Wp + (size_t)16 * C + k0);
#pragma unroll
    for (int i = 0; i < 4; ++i) {
      const f16x8 a = *reinterpret_cast<const f16x8*>(Ap + (size_t)16 * i * lda + k0);
      acc[i][0] = __builtin_amdgcn_mfma_f32_16x16x32_f16(a, b0, acc[i][0], 0, 0, 0);
      acc[i][1] = __builtin_amdgcn_mfma_f32_16x16x32_f16(a, b1, acc[i][1], 0, 0, 0);
    }
  }

#pragma unroll
  for (int j = 0; j < 2; ++j) {
    const int o = o0 + 16 * j + lr;
    const float bt = (MODE == 1) ? betap[o] : 0.f;
#pragma unroll
    for (int i = 0; i < 4; ++i) {
#pragma unroll
      for (int q = 0; q < 4; ++q) {
        const int r = m0 + 16 * i + lk * 4 + q;
        float t = acc[i][j][q];
        if (MODE == 1) { t += bt; t = fmaxf(t, NEG * t); }
        out[(size_t)r * ldout + o] = (_Float16)t;
      }
    }
  }
}

// ---------------- edge max: out[p,o] = max_k lrelu(z[nbr,o]-z[p,o]+beta[o]) --
// each thread owns CPT contiguous channels of one point (vector loads).
template <int O, int CPT>
__global__ __launch_bounds__(256) void edge_max_h(
    const _Float16* __restrict__ z, const int* __restrict__ idx,
    const float* __restrict__ betap, _Float16* __restrict__ out, int ldout) {
  constexpr int TPP = O / CPT;       // threads per point
  constexpr int PPB = 256 / TPP;     // points per block
  using VT = typename VecT<CPT>::T;
  const int t = threadIdx.x;
  const int p = blockIdx.x * PPB + t / TPP;
  const int cb = (t % TPP) * CPT;
  const int b = p >> 12;
  const int* ip = idx + (size_t)p * K_;
  float c[CPT], bt[CPT], mx[CPT];
  const VT vc = *reinterpret_cast<const VT*>(z + (size_t)p * O + cb);
#pragma unroll
  for (int q = 0; q < CPT; ++q) {
    c[q] = (float)vc[q]; bt[q] = betap[cb + q]; mx[q] = -1e30f;
  }
  const _Float16* zb = z + ((size_t)(b << 12)) * O;
#pragma unroll 5
  for (int k = 0; k < K_; ++k) {
    const int g = ip[k];
    const VT v = *reinterpret_cast<const VT*>(zb + (size_t)g * O + cb);
#pragma unroll
    for (int q = 0; q < CPT; ++q) {
      const float e = (float)v[q] - c[q] + bt[q];
      mx[q] = fmaxf(mx[q], fmaxf(e, NEG * e));
    }
  }
  VT vo;
#pragma unroll
  for (int q = 0; q < CPT; ++q) vo[q] = (_Float16)mx[q];
  *reinterpret_cast<VT*>(out + (size_t)p * ldout + cb) = vo;
}

// ---------------- final 128 -> 1 projection + lrelu --------------------------
__global__ __launch_bounds__(256) void final_dot(
    const _Float16* __restrict__ h,  // (M, 128) fp16
    const float* __restrict__ w7,    // (1, 128)
    float* __restrict__ out) {       // (M)
  const int lane = threadIdx.x & 63;
  const int p = (blockIdx.x << 2) + (threadIdx.x >> 6);
  const _Float16* hp = h + (size_t)p * 128;
  float s = (float)hp[lane] * w7[lane] + (float)hp[64 + lane] * w7[64 + lane];
#pragma unroll
  for (int off = 32; off; off >>= 1) s += __shfl_down(s, off, 64);
  if (lane == 0) out[p] = fmaxf(s, NEG * s);
}

// ---------------- launch -----------------------------------------------------
extern "C" void kernel_launch(void* const* d_in, const int* in_sizes, int n_in,
                              void* d_out, int out_size, void* d_ws, size_t ws_size,
                              hipStream_t stream) {
  const float* x  = (const float*)d_in[0];
  const int* idx  = (const int*)d_in[1];
  const float* w[7];
  for (int i = 0; i < 7; ++i) w[i] = (const float*)d_in[2 + i];
  const float* bn[24];
  for (int i = 0; i < 24; ++i) bn[i] = (const float*)d_in[9 + i];

  // ws map: P fp32 @0 (32KB) | Wh fp16 @32KB (~0.42MB) | z fp16 @1MB (16MB) |
  //         h512 fp16 @17MB (32MB).  h5 aliases z, h6 aliases h512.
  float* P       = (float*)d_ws;
  _Float16* Wh   = (_Float16*)((char*)d_ws + (32 << 10));
  _Float16* z    = (_Float16*)((char*)d_ws + (1 << 20));
  _Float16* h512 = (_Float16*)((char*)d_ws + (17u << 20));
  _Float16* h5 = z;
  _Float16* h6 = h512;

  setup_params<<<1, 256, 0, stream>>>(
      bn[0], bn[1], bn[2], bn[3],   bn[4], bn[5], bn[6], bn[7],
      bn[8], bn[9], bn[10], bn[11], bn[12], bn[13], bn[14], bn[15],
      bn[16], bn[17], bn[18], bn[19], bn[20], bn[21], bn[22], bn[23], P);
  convert_all<<<816, 256, 0, stream>>>(w[1], w[2], w[3], w[4], w[5], P, Wh);

  const float* inv1 = P + 0,    *bt1 = P + 64;
  const float* bt2 = P + 192;
  const float* bt3 = P + 384;
  const float* bt4 = P + 768;
  const float* bt5 = P + 1280;
  const float* bt6 = P + 1664;
  const _Float16* W2 = Wh + 0, *W3 = Wh + 4096, *W4 = Wh + 12288,
               *W5 = Wh + 45056, *W6 = Wh + 176128;

  // L1: edgeconv(3 -> 64)
  gemm_c3<<<M_ / 64, 256, 0, stream>>>(x, w[0], inv1, z);
  edge_max_h<64, 2><<<M_ / 8, 256, 0, stream>>>(z, idx, bt1, h512 + 0, 512);
  // L2: edgeconv(64 -> 64)
  gemm_mfma<0, 64><<<dim3(M_ / 128, 1), 256, 0, stream>>>(h512 + 0, 512, W2, nullptr, z, 64);
  edge_max_h<64, 2><<<M_ / 8, 256, 0, stream>>>(z, idx, bt2, h512 + 64, 512);
  // L3: edgeconv(64 -> 128)
  gemm_mfma<0, 64><<<dim3(M_ / 128, 2), 256, 0, stream>>>(h512 + 64, 512, W3, nullptr, z, 128);
  edge_max_h<128, 2><<<M_ / 4, 256, 0, stream>>>(z, idx, bt3, h512 + 128, 512);
  // L4: edgeconv(128 -> 256)
  gemm_mfma<0, 128><<<dim3(M_ / 128, 4), 256, 0, stream>>>(h512 + 128, 512, W4, nullptr, z, 256);
  edge_max_h<256, 4><<<M_ / 4, 256, 0, stream>>>(z, idx, bt4, h512 + 256, 512);
  // L5: pointconv(512 -> 256)
  gemm_mfma<1, 512><<<dim3(M_ / 128, 4), 256, 0, stream>>>(h512, 512, W5, bt5, h5, 256);
  // L6: pointconv(256 -> 128)
  gemm_mfma<1, 256><<<dim3(M_ / 128, 2), 256, 0, stream>>>(h5, 256, W6, bt6, h6, 128);
  // L7: final 128 -> 1 + lrelu
  final_dot<<<M_ / 4, 256, 0, stream>>>(h6, w[6], (float*)d_out);
}

// Round 4
// 144.083 us; speedup vs baseline: 2.6368x; 1.3357x over previous
//
#include <hip/hip_runtime.h>
#include <hip/hip_bf16.h>
#include <cstdint>
#include <cstddef>

#define EPS 1e-5f
#define NEG 0.2f

static constexpr int B_ = 8, N_ = 4096, K_ = 20, M_ = B_ * N_;  // M = 32768

typedef __attribute__((ext_vector_type(8))) _Float16 f16x8;
typedef __attribute__((ext_vector_type(4))) _Float16 f16x4;
typedef __attribute__((ext_vector_type(2))) _Float16 f16x2;
typedef __attribute__((ext_vector_type(4))) float f32x4;

template <int CPT> struct VecT;
template <> struct VecT<2> { using T = f16x2; };
template <> struct VecT<4> { using T = f16x4; };

// async global->LDS, 16B per lane; LDS dest = wave-uniform base + lane*16
__device__ __forceinline__ void gload_lds16(const _Float16* g, _Float16* l) {
  __builtin_amdgcn_global_load_lds(
      (const __attribute__((address_space(1))) uint32_t*)g,
      (__attribute__((address_space(3))) uint32_t*)l, 16, 0, 0);
}

// ---------------- BN param folding: inv = g*rsqrt(v+eps), beta = b - m*inv ----
__global__ void setup_params(
    const float* __restrict__ g1, const float* __restrict__ b1, const float* __restrict__ m1, const float* __restrict__ v1,
    const float* __restrict__ g2, const float* __restrict__ b2, const float* __restrict__ m2, const float* __restrict__ v2,
    const float* __restrict__ g3, const float* __restrict__ b3, const float* __restrict__ m3, const float* __restrict__ v3,
    const float* __restrict__ g4, const float* __restrict__ b4, const float* __restrict__ m4, const float* __restrict__ v4,
    const float* __restrict__ g5, const float* __restrict__ b5, const float* __restrict__ m5, const float* __restrict__ v5,
    const float* __restrict__ g6, const float* __restrict__ b6, const float* __restrict__ m6, const float* __restrict__ v6,
    float* __restrict__ P) {
  const float* G[6]  = {g1, g2, g3, g4, g5, g6};
  const float* Bb[6] = {b1, b2, b3, b4, b5, b6};
  const float* Mm[6] = {m1, m2, m3, m4, m5, m6};
  const float* Vv[6] = {v1, v2, v3, v4, v5, v6};
  const int Cs[6] = {64, 64, 128, 256, 256, 128};
  const int OI[6] = {0, 128, 256, 512, 1024, 1536};   // inv offsets
  const int OB[6] = {64, 192, 384, 768, 1280, 1664};  // beta offsets
  for (int l = 0; l < 6; ++l) {
    for (int c = threadIdx.x; c < Cs[l]; c += blockDim.x) {
      float iv = G[l][c] * rsqrtf(Vv[l][c] + EPS);
      P[OI[l] + c] = iv;
      P[OB[l] + c] = Bb[l][c] - Mm[l][c] * iv;
    }
  }
}

// ---------------- weight conversion: Wh[o][c] = f16(w[o][c] * inv[o]) --------
__global__ __launch_bounds__(256) void convert_all(
    const float* __restrict__ w2, const float* __restrict__ w3,
    const float* __restrict__ w4, const float* __restrict__ w5,
    const float* __restrict__ w6, const float* __restrict__ P,
    _Float16* __restrict__ Wh) {
  const int bid = blockIdx.x, tid = threadIdx.x;
  const float* w; const float* inv; _Float16* dst; int lc, base;
  if (bid < 16)       { w = w2; inv = P + 128;  dst = Wh + 0;      lc = 6; base = 0;   }
  else if (bid < 48)  { w = w3; inv = P + 256;  dst = Wh + 4096;   lc = 6; base = 16;  }
  else if (bid < 176) { w = w4; inv = P + 512;  dst = Wh + 12288;  lc = 7; base = 48;  }
  else if (bid < 688) { w = w5; inv = P + 1024; dst = Wh + 45056;  lc = 9; base = 176; }
  else                { w = w6; inv = P + 1536; dst = Wh + 176128; lc = 8; base = 688; }
  const int e = (bid - base) * 256 + tid;
  dst[e] = (_Float16)(w[e] * inv[e >> lc]);
}

// ---------------- layer-1 GEMM, C=3 special case -----------------------------
__global__ __launch_bounds__(256) void gemm_c3(
    const float* __restrict__ x,   // (B, 3, N)
    const float* __restrict__ w,   // (64, 3)
    const float* __restrict__ inv,
    _Float16* __restrict__ z) {    // (M, 64) fp16
  const int o  = threadIdx.x & 63;
  const int pi = threadIdx.x >> 6;
  const float w0 = w[o * 3 + 0], w1 = w[o * 3 + 1], w2 = w[o * 3 + 2];
  const float iv = inv[o];
  const int pbase = blockIdx.x * 64;
  const int b = pbase >> 12;
  const int nbase = pbase & (N_ - 1);
  const float* xb = x + (size_t)b * 3 * N_;
  for (int pj = pi; pj < 64; pj += 4) {
    const int n = nbase + pj;
    const float x0 = xb[n], x1 = xb[N_ + n], x2 = xb[2 * N_ + n];
    z[(size_t)(pbase + pj) * 64 + o] = (_Float16)((x0 * w0 + x1 * w1 + x2 * w2) * iv);
  }
}

// ---------------- fp16 MFMA GEMM, LDS double-buffered ------------------------
// out[m,o] = f( sum_c A[m,c] * W[o,c] )   (inv pre-folded into W)
// MODE 0: out = acc            MODE 1: t = acc + beta[o]; out = max(t, 0.2t)
// 256 thr = 4 waves (2x2). Tile BM x BO, BK=64. LDS stored fragment-contiguous:
// group g = 1KB = one MFMA fragment (64 lanes x 16B), so ds_read is
// uniform + lane*16B (conflict-free) and global_load_lds dest is linear.
template <int BM, int BO, int C, int MODE>
__global__ __launch_bounds__(256) void gemm_lds(
    const _Float16* __restrict__ A, int lda,
    const _Float16* __restrict__ W,       // (O, C) fp16, inv-folded
    const float* __restrict__ betap,
    _Float16* __restrict__ out, int ldout) {
  constexpr int NK = C / 64;            // K-steps
  constexpr int GA = BM / 8;            // A fragment-groups per K-step
  constexpr int GW = BO / 8;            // W fragment-groups
  constexpr int GT = GA + GW;
  constexpr int SB = (BM + BO) * 64;    // halves per buffer
  constexpr int MI = BM / 32, OJ = BO / 32;   // per-wave frag counts
  __shared__ _Float16 lds[2 * SB];

  const int lane = threadIdx.x & 63;
  const int wid  = threadIdx.x >> 6;
  const int wr = wid >> 1, wc = wid & 1;
  const int bm0 = blockIdx.x * BM;
  const int bo0 = blockIdx.y * BO;
  const int lr = lane & 15, lk = lane >> 4;

  const _Float16* Abase = A + (size_t)(bm0 + lr) * lda + lk * 8;
  const _Float16* Wbase = W + (size_t)(bo0 + lr) * C + lk * 8;

  f32x4 acc[MI][OJ];
#pragma unroll
  for (int i = 0; i < MI; ++i)
#pragma unroll
    for (int j = 0; j < OJ; ++j) acc[i][j] = (f32x4){0.f, 0.f, 0.f, 0.f};

  auto stage = [&](int buf, int k0) {
    _Float16* dst = &lds[buf * SB];
#pragma unroll
    for (int q = 0; q < GT / 4; ++q) {
      const int g = wid * (GT / 4) + q;
      const _Float16* src;
      if (g < GA) {
        const int i = g >> 1, s = g & 1;
        src = Abase + (size_t)16 * i * lda + k0 + s * 32;
      } else {
        const int o = (g - GA) >> 1, s = g & 1;
        src = Wbase + (size_t)16 * o * C + k0 + s * 32;
      }
      gload_lds16(src, dst + g * 512);
    }
  };

  auto compute = [&](int buf) {
    const _Float16* Ab = &lds[buf * SB];
    const _Float16* Wb = &lds[buf * SB + GA * 512];
#pragma unroll
    for (int s = 0; s < 2; ++s) {
      f16x8 av[MI], wv[OJ];
#pragma unroll
      for (int i = 0; i < MI; ++i)
        av[i] = *reinterpret_cast<const f16x8*>(Ab + ((wr * MI + i) * 2 + s) * 512 + lane * 8);
#pragma unroll
      for (int j = 0; j < OJ; ++j)
        wv[j] = *reinterpret_cast<const f16x8*>(Wb + ((wc * OJ + j) * 2 + s) * 512 + lane * 8);
#pragma unroll
      for (int i = 0; i < MI; ++i)
#pragma unroll
        for (int j = 0; j < OJ; ++j)
          acc[i][j] = __builtin_amdgcn_mfma_f32_16x16x32_f16(av[i], wv[j], acc[i][j], 0, 0, 0);
    }
  };

  stage(0, 0);
  __syncthreads();
#pragma unroll
  for (int t = 0; t < NK; ++t) {
    if (t + 1 < NK) stage((t + 1) & 1, (t + 1) * 64);
    compute(t & 1);
    __syncthreads();
  }

  // epilogue: C/D layout col = lane&15, row = (lane>>4)*4 + q
#pragma unroll
  for (int j = 0; j < OJ; ++j) {
    const int o = bo0 + wc * (BO / 2) + 16 * j + lr;
    const float bt = (MODE == 1) ? betap[o] : 0.f;
#pragma unroll
    for (int i = 0; i < MI; ++i) {
      const int r0 = bm0 + wr * (BM / 2) + 16 * i + lk * 4;
#pragma unroll
      for (int q = 0; q < 4; ++q) {
        float t = acc[i][j][q];
        if (MODE == 1) { t += bt; t = fmaxf(t, NEG * t); }
        out[(size_t)(r0 + q) * ldout + o] = (_Float16)t;
      }
    }
  }
}

// ---------------- edge max: out[p,o] = max_k lrelu(z[nbr,o]-z[p,o]+beta[o]) --
// batch = bid & 7 -> all blocks of one batch land on one XCD (round-robin
// dispatch), so the 2MB-max z slab stays in that XCD's 4MB L2.
template <int O, int CPT>
__global__ __launch_bounds__(256) void edge_max_h(
    const _Float16* __restrict__ z, const int* __restrict__ idx,
    const float* __restrict__ betap, _Float16* __restrict__ out, int ldout) {
  constexpr int TPP = O / CPT;       // threads per point
  constexpr int PPB = 256 / TPP;     // points per block
  using VT = typename VecT<CPT>::T;
  const int t = threadIdx.x;
  const int batch = blockIdx.x & 7;
  const int chunk = blockIdx.x >> 3;
  const int p = (batch << 12) + chunk * PPB + t / TPP;
  const int cb = (t % TPP) * CPT;
  const int* ip = idx + (size_t)p * K_;
  float c[CPT], bt[CPT], mx[CPT];
  const VT vc = *reinterpret_cast<const VT*>(z + (size_t)p * O + cb);
#pragma unroll
  for (int q = 0; q < CPT; ++q) {
    c[q] = (float)vc[q]; bt[q] = betap[cb + q]; mx[q] = -1e30f;
  }
  const _Float16* zb = z + ((size_t)(batch << 12)) * O;
#pragma unroll 5
  for (int k = 0; k < K_; ++k) {
    const int g = ip[k];
    const VT v = *reinterpret_cast<const VT*>(zb + (size_t)g * O + cb);
#pragma unroll
    for (int q = 0; q < CPT; ++q) {
      const float e = (float)v[q] - c[q] + bt[q];
      mx[q] = fmaxf(mx[q], fmaxf(e, NEG * e));
    }
  }
  VT vo;
#pragma unroll
  for (int q = 0; q < CPT; ++q) vo[q] = (_Float16)mx[q];
  *reinterpret_cast<VT*>(out + (size_t)p * ldout + cb) = vo;
}

// ---------------- final 128 -> 1 projection + lrelu --------------------------
__global__ __launch_bounds__(256) void final_dot(
    const _Float16* __restrict__ h,  // (M, 128) fp16
    const float* __restrict__ w7,    // (1, 128)
    float* __restrict__ out) {       // (M)
  const int lane = threadIdx.x & 63;
  const int p = (blockIdx.x << 2) + (threadIdx.x >> 6);
  const _Float16* hp = h + (size_t)p * 128;
  float s = (float)hp[lane] * w7[lane] + (float)hp[64 + lane] * w7[64 + lane];
#pragma unroll
  for (int off = 32; off; off >>= 1) s += __shfl_down(s, off, 64);
  if (lane == 0) out[p] = fmaxf(s, NEG * s);
}

// ---------------- launch -----------------------------------------------------
extern "C" void kernel_launch(void* const* d_in, const int* in_sizes, int n_in,
                              void* d_out, int out_size, void* d_ws, size_t ws_size,
                              hipStream_t stream) {
  const float* x  = (const float*)d_in[0];
  const int* idx  = (const int*)d_in[1];
  const float* w[7];
  for (int i = 0; i < 7; ++i) w[i] = (const float*)d_in[2 + i];
  const float* bn[24];
  for (int i = 0; i < 24; ++i) bn[i] = (const float*)d_in[9 + i];

  // ws map: P fp32 @0 (32KB) | Wh fp16 @32KB (~0.42MB) | z fp16 @1MB (16MB) |
  //         h512 fp16 @17MB (32MB).  h5 aliases z, h6 aliases h512.
  float* P       = (float*)d_ws;
  _Float16* Wh   = (_Float16*)((char*)d_ws + (32 << 10));
  _Float16* z    = (_Float16*)((char*)d_ws + (1 << 20));
  _Float16* h512 = (_Float16*)((char*)d_ws + (17u << 20));
  _Float16* h5 = z;
  _Float16* h6 = h512;

  setup_params<<<1, 256, 0, stream>>>(
      bn[0], bn[1], bn[2], bn[3],   bn[4], bn[5], bn[6], bn[7],
      bn[8], bn[9], bn[10], bn[11], bn[12], bn[13], bn[14], bn[15],
      bn[16], bn[17], bn[18], bn[19], bn[20], bn[21], bn[22], bn[23], P);
  convert_all<<<816, 256, 0, stream>>>(w[1], w[2], w[3], w[4], w[5], P, Wh);

  const float* inv1 = P + 0,    *bt1 = P + 64;
  const float* bt2 = P + 192;
  const float* bt3 = P + 384;
  const float* bt4 = P + 768;
  const float* bt5 = P + 1280;
  const float* bt6 = P + 1664;
  const _Float16* W2 = Wh + 0, *W3 = Wh + 4096, *W4 = Wh + 12288,
               *W5 = Wh + 45056, *W6 = Wh + 176128;

  // L1: edgeconv(3 -> 64)
  gemm_c3<<<M_ / 64, 256, 0, stream>>>(x, w[0], inv1, z);
  edge_max_h<64, 4><<<M_ / 16, 256, 0, stream>>>(z, idx, bt1, h512 + 0, 512);
  // L2: edgeconv(64 -> 64)
  gemm_lds<64, 64, 64, 0><<<dim3(M_ / 64, 1), 256, 0, stream>>>(h512 + 0, 512, W2, nullptr, z, 64);
  edge_max_h<64, 4><<<M_ / 16, 256, 0, stream>>>(z, idx, bt2, h512 + 64, 512);
  // L3: edgeconv(64 -> 128)
  gemm_lds<64, 128, 64, 0><<<dim3(M_ / 64, 1), 256, 0, stream>>>(h512 + 64, 512, W3, nullptr, z, 128);
  edge_max_h<128, 4><<<M_ / 8, 256, 0, stream>>>(z, idx, bt3, h512 + 128, 512);
  // L4: edgeconv(128 -> 256)
  gemm_lds<128, 128, 128, 0><<<dim3(M_ / 128, 2), 256, 0, stream>>>(h512 + 128, 512, W4, nullptr, z, 256);
  edge_max_h<256, 4><<<M_ / 4, 256, 0, stream>>>(z, idx, bt4, h512 + 256, 512);
  // L5: pointconv(512 -> 256)
  gemm_lds<128, 128, 512, 1><<<dim3(M_ / 128, 2), 256, 0, stream>>>(h512, 512, W5, bt5, h5, 256);
  // L6: pointconv(256 -> 128)
  gemm_lds<64, 128, 256, 1><<<dim3(M_ / 64, 1), 256, 0, stream>>>(h5, 256, W6, bt6, h6, 128);
  // L7: final 128 -> 1 + lrelu
  final_dot<<<M_ / 4, 256, 0, stream>>>(h6, w[6], (float*)d_out);
}

// Round 5
// 113.233 us; speedup vs baseline: 3.3552x; 1.2725x over previous
//
#include <hip/hip_runtime.h>
#include <hip/hip_bf16.h>
#include <cstdint>
#include <cstddef>

#define EPS 1e-5f
#define NEG 0.2f

static constexpr int B_ = 8, N_ = 4096, K_ = 20, M_ = B_ * N_;  // M = 32768

typedef __attribute__((ext_vector_type(8))) _Float16 f16x8;
typedef __attribute__((ext_vector_type(4))) float f32x4;

// async global->LDS, 16B per lane; LDS dest = wave-uniform base + lane*16
__device__ __forceinline__ void gload_lds16(const _Float16* g, _Float16* l) {
  __builtin_amdgcn_global_load_lds(
      (const __attribute__((address_space(1))) uint32_t*)g,
      (__attribute__((address_space(3))) uint32_t*)l, 16, 0, 0);
}

// ---------------- BN param folding: inv = g*rsqrt(v+eps), beta = b - m*inv ----
__global__ void setup_params(
    const float* __restrict__ g1, const float* __restrict__ b1, const float* __restrict__ m1, const float* __restrict__ v1,
    const float* __restrict__ g2, const float* __restrict__ b2, const float* __restrict__ m2, const float* __restrict__ v2,
    const float* __restrict__ g3, const float* __restrict__ b3, const float* __restrict__ m3, const float* __restrict__ v3,
    const float* __restrict__ g4, const float* __restrict__ b4, const float* __restrict__ m4, const float* __restrict__ v4,
    const float* __restrict__ g5, const float* __restrict__ b5, const float* __restrict__ m5, const float* __restrict__ v5,
    const float* __restrict__ g6, const float* __restrict__ b6, const float* __restrict__ m6, const float* __restrict__ v6,
    float* __restrict__ P) {
  const float* G[6]  = {g1, g2, g3, g4, g5, g6};
  const float* Bb[6] = {b1, b2, b3, b4, b5, b6};
  const float* Mm[6] = {m1, m2, m3, m4, m5, m6};
  const float* Vv[6] = {v1, v2, v3, v4, v5, v6};
  const int Cs[6] = {64, 64, 128, 256, 256, 128};
  const int OI[6] = {0, 128, 256, 512, 1024, 1536};   // inv offsets
  const int OB[6] = {64, 192, 384, 768, 1280, 1664};  // beta offsets
  for (int l = 0; l < 6; ++l) {
    for (int c = threadIdx.x; c < Cs[l]; c += blockDim.x) {
      float iv = G[l][c] * rsqrtf(Vv[l][c] + EPS);
      P[OI[l] + c] = iv;
      P[OB[l] + c] = Bb[l][c] - Mm[l][c] * iv;
    }
  }
}

// ---------------- weight conversion: Wh[o][c] = f16(w[o][c] * inv[o]) --------
__global__ __launch_bounds__(256) void convert_all(
    const float* __restrict__ w2, const float* __restrict__ w3,
    const float* __restrict__ w4, const float* __restrict__ w5,
    const float* __restrict__ w6, const float* __restrict__ P,
    _Float16* __restrict__ Wh) {
  const int bid = blockIdx.x, tid = threadIdx.x;
  const float* w; const float* inv; _Float16* dst; int lc, base;
  if (bid < 16)       { w = w2; inv = P + 128;  dst = Wh + 0;      lc = 6; base = 0;   }
  else if (bid < 48)  { w = w3; inv = P + 256;  dst = Wh + 4096;   lc = 6; base = 16;  }
  else if (bid < 176) { w = w4; inv = P + 512;  dst = Wh + 12288;  lc = 7; base = 48;  }
  else if (bid < 688) { w = w5; inv = P + 1024; dst = Wh + 45056;  lc = 9; base = 176; }
  else                { w = w6; inv = P + 1536; dst = Wh + 176128; lc = 8; base = 688; }
  const int e = (bid - base) * 256 + tid;
  dst[e] = (_Float16)(w[e] * inv[e >> lc]);
}

// ---------------- layer-1 GEMM, C=3 special case -----------------------------
__global__ __launch_bounds__(256) void gemm_c3(
    const float* __restrict__ x,   // (B, 3, N)
    const float* __restrict__ w,   // (64, 3)
    const float* __restrict__ inv,
    _Float16* __restrict__ z) {    // (M, 64) fp16
  const int o  = threadIdx.x & 63;
  const int pi = threadIdx.x >> 6;
  const float w0 = w[o * 3 + 0], w1 = w[o * 3 + 1], w2 = w[o * 3 + 2];
  const float iv = inv[o];
  const int pbase = blockIdx.x * 64;
  const int b = pbase >> 12;
  const int nbase = pbase & (N_ - 1);
  const float* xb = x + (size_t)b * 3 * N_;
  for (int pj = pi; pj < 64; pj += 4) {
    const int n = nbase + pj;
    const float x0 = xb[n], x1 = xb[N_ + n], x2 = xb[2 * N_ + n];
    z[(size_t)(pbase + pj) * 64 + o] = (_Float16)((x0 * w0 + x1 * w1 + x2 * w2) * iv);
  }
}

// ---------------- fp16 MFMA GEMM, 2-buffer LDS (small C) ---------------------
// LDS fragment-contiguous: group = 1KB = one MFMA fragment (64 lanes x 16B).
template <int BM, int BO, int C, int MODE>
__global__ __launch_bounds__(256) void gemm_lds(
    const _Float16* __restrict__ A, int lda,
    const _Float16* __restrict__ W,       // (O, C) fp16, inv-folded
    const float* __restrict__ betap,
    _Float16* __restrict__ out, int ldout) {
  constexpr int NK = C / 64;
  constexpr int GA = BM / 8;
  constexpr int GW = BO / 8;
  constexpr int GT = GA + GW;
  constexpr int SB = (BM + BO) * 64;
  constexpr int MI = BM / 32, OJ = BO / 32;
  __shared__ _Float16 lds[2 * SB];

  const int lane = threadIdx.x & 63;
  const int wid  = threadIdx.x >> 6;
  const int wr = wid >> 1, wc = wid & 1;
  const int bm0 = blockIdx.x * BM;
  const int bo0 = blockIdx.y * BO;
  const int lr = lane & 15, lk = lane >> 4;

  const _Float16* Abase = A + (size_t)(bm0 + lr) * lda + lk * 8;
  const _Float16* Wbase = W + (size_t)(bo0 + lr) * C + lk * 8;

  f32x4 acc[MI][OJ];
#pragma unroll
  for (int i = 0; i < MI; ++i)
#pragma unroll
    for (int j = 0; j < OJ; ++j) acc[i][j] = (f32x4){0.f, 0.f, 0.f, 0.f};

  auto stage = [&](int buf, int k0) {
    _Float16* dst = &lds[buf * SB];
#pragma unroll
    for (int q = 0; q < GT / 4; ++q) {
      const int g = wid * (GT / 4) + q;
      const _Float16* src;
      if (g < GA) {
        const int i = g >> 1, s = g & 1;
        src = Abase + (size_t)16 * i * lda + k0 + s * 32;
      } else {
        const int o = (g - GA) >> 1, s = g & 1;
        src = Wbase + (size_t)16 * o * C + k0 + s * 32;
      }
      gload_lds16(src, dst + g * 512);
    }
  };

  auto compute = [&](int buf) {
    const _Float16* Ab = &lds[buf * SB];
    const _Float16* Wb = &lds[buf * SB + GA * 512];
#pragma unroll
    for (int s = 0; s < 2; ++s) {
      f16x8 av[MI], wv[OJ];
#pragma unroll
      for (int i = 0; i < MI; ++i)
        av[i] = *reinterpret_cast<const f16x8*>(Ab + ((wr * MI + i) * 2 + s) * 512 + lane * 8);
#pragma unroll
      for (int j = 0; j < OJ; ++j)
        wv[j] = *reinterpret_cast<const f16x8*>(Wb + ((wc * OJ + j) * 2 + s) * 512 + lane * 8);
#pragma unroll
      for (int i = 0; i < MI; ++i)
#pragma unroll
        for (int j = 0; j < OJ; ++j)
          acc[i][j] = __builtin_amdgcn_mfma_f32_16x16x32_f16(av[i], wv[j], acc[i][j], 0, 0, 0);
    }
  };

  stage(0, 0);
  __syncthreads();
#pragma unroll
  for (int t = 0; t < NK; ++t) {
    if (t + 1 < NK) stage((t + 1) & 1, (t + 1) * 64);
    compute(t & 1);
    __syncthreads();
  }

#pragma unroll
  for (int j = 0; j < OJ; ++j) {
    const int o = bo0 + wc * (BO / 2) + 16 * j + lr;
    const float bt = (MODE == 1) ? betap[o] : 0.f;
#pragma unroll
    for (int i = 0; i < MI; ++i) {
      const int r0 = bm0 + wr * (BM / 2) + 16 * i + lk * 4;
#pragma unroll
      for (int q = 0; q < 4; ++q) {
        float t = acc[i][j][q];
        if (MODE == 1) { t += bt; t = fmaxf(t, NEG * t); }
        out[(size_t)(r0 + q) * ldout + o] = (_Float16)t;
      }
    }
  }
}

// ---------------- fp16 MFMA GEMM, 4-buffer counted-vmcnt pipeline ------------
// BK=32, ring of 4 LDS buffers; stage(t+2) issued during compute(t); waits are
// counted (vmcnt(8)) so prefetches stay in flight across barriers (T3+T4).
template <int BM, int BO, int C, int MODE>
__global__ __launch_bounds__(256) void gemm_pipe(
    const _Float16* __restrict__ A, int lda,
    const _Float16* __restrict__ W,
    const float* __restrict__ betap,
    _Float16* __restrict__ out, int ldout) {
  constexpr int NK = C / 32;
  constexpr int GA = BM / 16;           // A groups per K-step (16 rows x 32k = 1KB)
  constexpr int GW = BO / 16;
  constexpr int GT = GA + GW;           // 16 for 128x128
  constexpr int GP = GT / 4;            // groups per wave = 4
  constexpr int SB = (BM + BO) * 32;    // halves per buffer (8192)
  constexpr int MI = BM / 32, OJ = BO / 32;
  __shared__ _Float16 lds[4 * SB];

  const int lane = threadIdx.x & 63;
  const int wid  = threadIdx.x >> 6;
  const int wr = wid >> 1, wc = wid & 1;
  const int bm0 = blockIdx.x * BM;
  const int bo0 = blockIdx.y * BO;
  const int lr = lane & 15, lk = lane >> 4;

  const _Float16* Abase = A + (size_t)(bm0 + lr) * lda + lk * 8;
  const _Float16* Wbase = W + (size_t)(bo0 + lr) * C + lk * 8;

  f32x4 acc[MI][OJ];
#pragma unroll
  for (int i = 0; i < MI; ++i)
#pragma unroll
    for (int j = 0; j < OJ; ++j) acc[i][j] = (f32x4){0.f, 0.f, 0.f, 0.f};

  auto stage = [&](int buf, int k0) {
    _Float16* dst = &lds[buf * SB];
#pragma unroll
    for (int q = 0; q < GP; ++q) {
      const int g = wid * GP + q;
      const _Float16* src = (g < GA)
          ? Abase + (size_t)16 * g * lda + k0
          : Wbase + (size_t)16 * (g - GA) * C + k0;
      gload_lds16(src, dst + g * 512);
    }
  };

  auto compute = [&](int buf) {
    const _Float16* Ab = &lds[buf * SB];
    const _Float16* Wb = &lds[buf * SB + GA * 512];
    f16x8 av[MI], wv[OJ];
#pragma unroll
    for (int i = 0; i < MI; ++i)
      av[i] = *reinterpret_cast<const f16x8*>(Ab + (wr * MI + i) * 512 + lane * 8);
#pragma unroll
    for (int j = 0; j < OJ; ++j)
      wv[j] = *reinterpret_cast<const f16x8*>(Wb + (wc * OJ + j) * 512 + lane * 8);
#pragma unroll
    for (int i = 0; i < MI; ++i)
#pragma unroll
      for (int j = 0; j < OJ; ++j)
        acc[i][j] = __builtin_amdgcn_mfma_f32_16x16x32_f16(av[i], wv[j], acc[i][j], 0, 0, 0);
  };

  stage(0, 0);
  stage(1, 32);
#pragma unroll
  for (int t = 0; t < NK; ++t) {
    if (t + 2 < NK) {
      stage((t + 2) & 3, (t + 2) * 32);
      asm volatile("s_waitcnt vmcnt(8)" ::: "memory");   // keep t+1,t+2 in flight
    } else if (t + 1 < NK) {
      asm volatile("s_waitcnt vmcnt(4)" ::: "memory");
    } else {
      asm volatile("s_waitcnt vmcnt(0)" ::: "memory");
    }
    __builtin_amdgcn_s_barrier();
    compute(t & 3);
  }

#pragma unroll
  for (int j = 0; j < OJ; ++j) {
    const int o = bo0 + wc * (BO / 2) + 16 * j + lr;
    const float bt = (MODE == 1) ? betap[o] : 0.f;
#pragma unroll
    for (int i = 0; i < MI; ++i) {
      const int r0 = bm0 + wr * (BM / 2) + 16 * i + lk * 4;
#pragma unroll
      for (int q = 0; q < 4; ++q) {
        float t = acc[i][j][q];
        if (MODE == 1) { t += bt; t = fmaxf(t, NEG * t); }
        out[(size_t)(r0 + q) * ldout + o] = (_Float16)t;
      }
    }
  }
}

// ---------------- edge max, distributed: lrelu(max_k z[nbr] - z[p] + beta) ---
// 8 channels/thread (16B loads); inner loop is pure packed fp16 max.
// batch = bid & 7 -> one batch per XCD (L2-resident z slab).
template <int O>
__global__ __launch_bounds__(256) void edge_max8(
    const _Float16* __restrict__ z, const int* __restrict__ idx,
    const float* __restrict__ betap, _Float16* __restrict__ out, int ldout) {
  constexpr int TPP = O / 8;         // threads per point
  constexpr int PPB = 256 / TPP;     // points per block
  const int t = threadIdx.x;
  const int batch = blockIdx.x & 7;
  const int chunk = blockIdx.x >> 3;
  const int p = (batch << 12) + chunk * PPB + t / TPP;
  const int cb = (t % TPP) * 8;
  const int* ip = idx + (size_t)p * K_;
  const _Float16* zb = z + ((size_t)(batch << 12)) * O;

  f16x8 mx = *reinterpret_cast<const f16x8*>(zb + (size_t)ip[0] * O + cb);
#pragma unroll
  for (int k = 1; k < K_; ++k) {
    const f16x8 v = *reinterpret_cast<const f16x8*>(zb + (size_t)ip[k] * O + cb);
#pragma unroll
    for (int q = 0; q < 8; ++q) mx[q] = v[q] > mx[q] ? v[q] : mx[q];
  }
  const f16x8 vc = *reinterpret_cast<const f16x8*>(z + (size_t)p * O + cb);
  f16x8 vo;
#pragma unroll
  for (int q = 0; q < 8; ++q) {
    const float e = (float)mx[q] - (float)vc[q] + betap[cb + q];
    vo[q] = (_Float16)fmaxf(e, NEG * e);
  }
  *reinterpret_cast<f16x8*>(out + (size_t)p * ldout + cb) = vo;
}

// ---------------- final 128 -> 1 projection + lrelu --------------------------
__global__ __launch_bounds__(256) void final_dot(
    const _Float16* __restrict__ h,  // (M, 128) fp16
    const float* __restrict__ w7,    // (1, 128)
    float* __restrict__ out) {       // (M)
  const int lane = threadIdx.x & 63;
  const int p = (blockIdx.x << 2) + (threadIdx.x >> 6);
  const _Float16* hp = h + (size_t)p * 128;
  float s = (float)hp[lane] * w7[lane] + (float)hp[64 + lane] * w7[64 + lane];
#pragma unroll
  for (int off = 32; off; off >>= 1) s += __shfl_down(s, off, 64);
  if (lane == 0) out[p] = fmaxf(s, NEG * s);
}

// ---------------- launch -----------------------------------------------------
extern "C" void kernel_launch(void* const* d_in, const int* in_sizes, int n_in,
                              void* d_out, int out_size, void* d_ws, size_t ws_size,
                              hipStream_t stream) {
  const float* x  = (const float*)d_in[0];
  const int* idx  = (const int*)d_in[1];
  const float* w[7];
  for (int i = 0; i < 7; ++i) w[i] = (const float*)d_in[2 + i];
  const float* bn[24];
  for (int i = 0; i < 24; ++i) bn[i] = (const float*)d_in[9 + i];

  // ws map: P fp32 @0 (32KB) | Wh fp16 @32KB (~0.42MB) | z fp16 @1MB (16MB) |
  //         h512 fp16 @17MB (32MB).  h5 aliases z, h6 aliases h512.
  float* P       = (float*)d_ws;
  _Float16* Wh   = (_Float16*)((char*)d_ws + (32 << 10));
  _Float16* z    = (_Float16*)((char*)d_ws + (1 << 20));
  _Float16* h512 = (_Float16*)((char*)d_ws + (17u << 20));
  _Float16* h5 = z;
  _Float16* h6 = h512;

  setup_params<<<1, 256, 0, stream>>>(
      bn[0], bn[1], bn[2], bn[3],   bn[4], bn[5], bn[6], bn[7],
      bn[8], bn[9], bn[10], bn[11], bn[12], bn[13], bn[14], bn[15],
      bn[16], bn[17], bn[18], bn[19], bn[20], bn[21], bn[22], bn[23], P);
  convert_all<<<816, 256, 0, stream>>>(w[1], w[2], w[3], w[4], w[5], P, Wh);

  const float* inv1 = P + 0,    *bt1 = P + 64;
  const float* bt2 = P + 192;
  const float* bt3 = P + 384;
  const float* bt4 = P + 768;
  const float* bt5 = P + 1280;
  const float* bt6 = P + 1664;
  const _Float16* W2 = Wh + 0, *W3 = Wh + 4096, *W4 = Wh + 12288,
               *W5 = Wh + 45056, *W6 = Wh + 176128;

  // L1: edgeconv(3 -> 64)
  gemm_c3<<<M_ / 64, 256, 0, stream>>>(x, w[0], inv1, z);
  edge_max8<64><<<M_ / 32, 256, 0, stream>>>(z, idx, bt1, h512 + 0, 512);
  // L2: edgeconv(64 -> 64)
  gemm_lds<64, 64, 64, 0><<<dim3(M_ / 64, 1), 256, 0, stream>>>(h512 + 0, 512, W2, nullptr, z, 64);
  edge_max8<64><<<M_ / 32, 256, 0, stream>>>(z, idx, bt2, h512 + 64, 512);
  // L3: edgeconv(64 -> 128)
  gemm_lds<64, 128, 64, 0><<<dim3(M_ / 64, 1), 256, 0, stream>>>(h512 + 64, 512, W3, nullptr, z, 128);
  edge_max8<128><<<M_ / 16, 256, 0, stream>>>(z, idx, bt3, h512 + 128, 512);
  // L4: edgeconv(128 -> 256)
  gemm_pipe<128, 128, 128, 0><<<dim3(M_ / 128, 2), 256, 0, stream>>>(h512 + 128, 512, W4, nullptr, z, 256);
  edge_max8<256><<<M_ / 8, 256, 0, stream>>>(z, idx, bt4, h512 + 256, 512);
  // L5: pointconv(512 -> 256)
  gemm_pipe<128, 128, 512, 1><<<dim3(M_ / 128, 2), 256, 0, stream>>>(h512, 512, W5, bt5, h5, 256);
  // L6: pointconv(256 -> 128)
  gemm_pipe<128, 128, 256, 1><<<dim3(M_ / 128, 1), 256, 0, stream>>>(h5, 256, W6, bt6, h6, 128);
  // L7: final 128 -> 1 + lrelu
  final_dot<<<M_ / 4, 256, 0, stream>>>(h6, w[6], (float*)d_out);
}

// Round 6
// 106.078 us; speedup vs baseline: 3.5815x; 1.0674x over previous
//
#include <hip/hip_runtime.h>
#include <hip/hip_bf16.h>
#include <cstdint>
#include <cstddef>

#define EPS 1e-5f
#define NEG 0.2f

static constexpr int B_ = 8, N_ = 4096, K_ = 20, M_ = B_ * N_;  // M = 32768

typedef __attribute__((ext_vector_type(8))) _Float16 f16x8;
typedef __attribute__((ext_vector_type(4))) float f32x4;

// async global->LDS, 16B per lane; LDS dest = wave-uniform base + lane*16
__device__ __forceinline__ void gload_lds16(const _Float16* g, _Float16* l) {
  __builtin_amdgcn_global_load_lds(
      (const __attribute__((address_space(1))) uint32_t*)g,
      (__attribute__((address_space(3))) uint32_t*)l, 16, 0, 0);
}

// ---------------- prep: weight fold (blocks 0..815) + BN params (block 816) --
// Wh[o][c] = f16(w[o][c] * g[o]*rsqrt(v[o]+eps)); P = {inv,beta} per layer.
__global__ __launch_bounds__(256) void prep(
    const float* __restrict__ w2, const float* __restrict__ w3,
    const float* __restrict__ w4, const float* __restrict__ w5,
    const float* __restrict__ w6,
    const float* __restrict__ g1, const float* __restrict__ b1, const float* __restrict__ m1, const float* __restrict__ v1,
    const float* __restrict__ g2, const float* __restrict__ b2, const float* __restrict__ m2, const float* __restrict__ v2,
    const float* __restrict__ g3, const float* __restrict__ b3, const float* __restrict__ m3, const float* __restrict__ v3,
    const float* __restrict__ g4, const float* __restrict__ b4, const float* __restrict__ m4, const float* __restrict__ v4,
    const float* __restrict__ g5, const float* __restrict__ b5, const float* __restrict__ m5, const float* __restrict__ v5,
    const float* __restrict__ g6, const float* __restrict__ b6, const float* __restrict__ m6, const float* __restrict__ v6,
    float* __restrict__ P, _Float16* __restrict__ Wh) {
  const int bid = blockIdx.x, tid = threadIdx.x;
  if (bid == 816) {
    const float* G[6]  = {g1, g2, g3, g4, g5, g6};
    const float* Bb[6] = {b1, b2, b3, b4, b5, b6};
    const float* Mm[6] = {m1, m2, m3, m4, m5, m6};
    const float* Vv[6] = {v1, v2, v3, v4, v5, v6};
    const int Cs[6] = {64, 64, 128, 256, 256, 128};
    const int OI[6] = {0, 128, 256, 512, 1024, 1536};
    const int OB[6] = {64, 192, 384, 768, 1280, 1664};
    for (int l = 0; l < 6; ++l) {
      for (int c = tid; c < Cs[l]; c += 256) {
        float iv = G[l][c] * rsqrtf(Vv[l][c] + EPS);
        P[OI[l] + c] = iv;
        P[OB[l] + c] = Bb[l][c] - Mm[l][c] * iv;
      }
    }
    return;
  }
  const float* w; const float* g; const float* v; _Float16* dst; int lc, base;
  if (bid < 16)       { w = w2; g = g2; v = v2; dst = Wh + 0;      lc = 6; base = 0;   }
  else if (bid < 48)  { w = w3; g = g3; v = v3; dst = Wh + 4096;   lc = 6; base = 16;  }
  else if (bid < 176) { w = w4; g = g4; v = v4; dst = Wh + 12288;  lc = 7; base = 48;  }
  else if (bid < 688) { w = w5; g = g5; v = v5; dst = Wh + 45056;  lc = 9; base = 176; }
  else                { w = w6; g = g6; v = v6; dst = Wh + 176128; lc = 8; base = 688; }
  const int e = (bid - base) * 256 + tid;
  const int o = e >> lc;
  dst[e] = (_Float16)(w[e] * (g[o] * rsqrtf(v[o] + EPS)));
}

// ---------------- layer-1 GEMM, C=3 special case -----------------------------
__global__ __launch_bounds__(256) void gemm_c3(
    const float* __restrict__ x,   // (B, 3, N)
    const float* __restrict__ w,   // (64, 3)
    const float* __restrict__ inv,
    _Float16* __restrict__ z) {    // (M, 64) fp16
  const int o  = threadIdx.x & 63;
  const int pi = threadIdx.x >> 6;
  const float w0 = w[o * 3 + 0], w1 = w[o * 3 + 1], w2 = w[o * 3 + 2];
  const float iv = inv[o];
  const int pbase = blockIdx.x * 64;
  const int b = pbase >> 12;
  const int nbase = pbase & (N_ - 1);
  const float* xb = x + (size_t)b * 3 * N_;
  for (int pj = pi; pj < 64; pj += 4) {
    const int n = nbase + pj;
    const float x0 = xb[n], x1 = xb[N_ + n], x2 = xb[2 * N_ + n];
    z[(size_t)(pbase + pj) * 64 + o] = (_Float16)((x0 * w0 + x1 * w1 + x2 * w2) * iv);
  }
}

// ---------------- fp16 MFMA GEMM, 2-buffer LDS (small C) ---------------------
template <int BM, int BO, int C, int MODE>
__global__ __launch_bounds__(256) void gemm_lds(
    const _Float16* __restrict__ A, int lda,
    const _Float16* __restrict__ W,
    const float* __restrict__ betap,
    _Float16* __restrict__ out, int ldout) {
  constexpr int NK = C / 64;
  constexpr int GA = BM / 8;
  constexpr int GW = BO / 8;
  constexpr int GT = GA + GW;
  constexpr int SB = (BM + BO) * 64;
  constexpr int MI = BM / 32, OJ = BO / 32;
  __shared__ _Float16 lds[2 * SB];

  const int lane = threadIdx.x & 63;
  const int wid  = threadIdx.x >> 6;
  const int wr = wid >> 1, wc = wid & 1;
  const int bm0 = blockIdx.x * BM;
  const int bo0 = blockIdx.y * BO;
  const int lr = lane & 15, lk = lane >> 4;

  const _Float16* Abase = A + (size_t)(bm0 + lr) * lda + lk * 8;
  const _Float16* Wbase = W + (size_t)(bo0 + lr) * C + lk * 8;

  f32x4 acc[MI][OJ];
#pragma unroll
  for (int i = 0; i < MI; ++i)
#pragma unroll
    for (int j = 0; j < OJ; ++j) acc[i][j] = (f32x4){0.f, 0.f, 0.f, 0.f};

  auto stage = [&](int buf, int k0) {
    _Float16* dst = &lds[buf * SB];
#pragma unroll
    for (int q = 0; q < GT / 4; ++q) {
      const int g = wid * (GT / 4) + q;
      const _Float16* src;
      if (g < GA) {
        const int i = g >> 1, s = g & 1;
        src = Abase + (size_t)16 * i * lda + k0 + s * 32;
      } else {
        const int o = (g - GA) >> 1, s = g & 1;
        src = Wbase + (size_t)16 * o * C + k0 + s * 32;
      }
      gload_lds16(src, dst + g * 512);
    }
  };

  auto compute = [&](int buf) {
    const _Float16* Ab = &lds[buf * SB];
    const _Float16* Wb = &lds[buf * SB + GA * 512];
#pragma unroll
    for (int s = 0; s < 2; ++s) {
      f16x8 av[MI], wv[OJ];
#pragma unroll
      for (int i = 0; i < MI; ++i)
        av[i] = *reinterpret_cast<const f16x8*>(Ab + ((wr * MI + i) * 2 + s) * 512 + lane * 8);
#pragma unroll
      for (int j = 0; j < OJ; ++j)
        wv[j] = *reinterpret_cast<const f16x8*>(Wb + ((wc * OJ + j) * 2 + s) * 512 + lane * 8);
#pragma unroll
      for (int i = 0; i < MI; ++i)
#pragma unroll
        for (int j = 0; j < OJ; ++j)
          acc[i][j] = __builtin_amdgcn_mfma_f32_16x16x32_f16(av[i], wv[j], acc[i][j], 0, 0, 0);
    }
  };

  stage(0, 0);
  __syncthreads();
#pragma unroll
  for (int t = 0; t < NK; ++t) {
    if (t + 1 < NK) stage((t + 1) & 1, (t + 1) * 64);
    compute(t & 1);
    __syncthreads();
  }

#pragma unroll
  for (int j = 0; j < OJ; ++j) {
    const int o = bo0 + wc * (BO / 2) + 16 * j + lr;
    const float bt = (MODE == 1) ? betap[o] : 0.f;
#pragma unroll
    for (int i = 0; i < MI; ++i) {
      const int r0 = bm0 + wr * (BM / 2) + 16 * i + lk * 4;
#pragma unroll
      for (int q = 0; q < 4; ++q) {
        float t = acc[i][j][q];
        if (MODE == 1) { t += bt; t = fmaxf(t, NEG * t); }
        out[(size_t)(r0 + q) * ldout + o] = (_Float16)t;
      }
    }
  }
}

// ---------------- fp16 MFMA GEMM, 4-buffer counted-vmcnt pipeline ------------
// MODE 0: out=acc  MODE 1: lrelu(acc+beta)  MODE 2: MODE1 then fused dot w7
template <int BM, int BO, int C, int MODE>
__global__ __launch_bounds__(256) void gemm_pipe(
    const _Float16* __restrict__ A, int lda,
    const _Float16* __restrict__ W,
    const float* __restrict__ betap,
    _Float16* __restrict__ out, int ldout,
    const float* __restrict__ w7, float* __restrict__ dout) {
  constexpr int NK = C / 32;
  constexpr int GA = BM / 16;
  constexpr int GW = BO / 16;
  constexpr int GT = GA + GW;
  constexpr int GP = GT / 4;
  constexpr int SB = (BM + BO) * 32;
  constexpr int MI = BM / 32, OJ = BO / 32;
  __shared__ _Float16 lds[4 * SB];

  const int lane = threadIdx.x & 63;
  const int wid  = threadIdx.x >> 6;
  const int wr = wid >> 1, wc = wid & 1;
  const int bm0 = blockIdx.x * BM;
  const int bo0 = blockIdx.y * BO;
  const int lr = lane & 15, lk = lane >> 4;

  const _Float16* Abase = A + (size_t)(bm0 + lr) * lda + lk * 8;
  const _Float16* Wbase = W + (size_t)(bo0 + lr) * C + lk * 8;

  f32x4 acc[MI][OJ];
#pragma unroll
  for (int i = 0; i < MI; ++i)
#pragma unroll
    for (int j = 0; j < OJ; ++j) acc[i][j] = (f32x4){0.f, 0.f, 0.f, 0.f};

  auto stage = [&](int buf, int k0) {
    _Float16* dst = &lds[buf * SB];
#pragma unroll
    for (int q = 0; q < GP; ++q) {
      const int g = wid * GP + q;
      const _Float16* src = (g < GA)
          ? Abase + (size_t)16 * g * lda + k0
          : Wbase + (size_t)16 * (g - GA) * C + k0;
      gload_lds16(src, dst + g * 512);
    }
  };

  auto compute = [&](int buf) {
    const _Float16* Ab = &lds[buf * SB];
    const _Float16* Wb = &lds[buf * SB + GA * 512];
    f16x8 av[MI], wv[OJ];
#pragma unroll
    for (int i = 0; i < MI; ++i)
      av[i] = *reinterpret_cast<const f16x8*>(Ab + (wr * MI + i) * 512 + lane * 8);
#pragma unroll
    for (int j = 0; j < OJ; ++j)
      wv[j] = *reinterpret_cast<const f16x8*>(Wb + (wc * OJ + j) * 512 + lane * 8);
#pragma unroll
    for (int i = 0; i < MI; ++i)
#pragma unroll
      for (int j = 0; j < OJ; ++j)
        acc[i][j] = __builtin_amdgcn_mfma_f32_16x16x32_f16(av[i], wv[j], acc[i][j], 0, 0, 0);
  };

  stage(0, 0);
  stage(1, 32);
#pragma unroll
  for (int t = 0; t < NK; ++t) {
    if (t + 2 < NK) {
      stage((t + 2) & 3, (t + 2) * 32);
      asm volatile("s_waitcnt vmcnt(8)" ::: "memory");
    } else if (t + 1 < NK) {
      asm volatile("s_waitcnt vmcnt(4)" ::: "memory");
    } else {
      asm volatile("s_waitcnt vmcnt(0)" ::: "memory");
    }
    __builtin_amdgcn_s_barrier();
    compute(t & 3);
  }

  if constexpr (MODE == 2) {
    // fused 128 -> 1 dot: rowdot over this wave's 64 cols, then cross-wave LDS
    __shared__ float dotbuf[128][2];
    float rowdot[MI][4];
#pragma unroll
    for (int i = 0; i < MI; ++i)
#pragma unroll
      for (int q = 0; q < 4; ++q) rowdot[i][q] = 0.f;
#pragma unroll
    for (int j = 0; j < OJ; ++j) {
      const int o = wc * (BO / 2) + 16 * j + lr;
      const float bt = betap[o];
      const float wf = w7[o];
#pragma unroll
      for (int i = 0; i < MI; ++i)
#pragma unroll
        for (int q = 0; q < 4; ++q) {
          float t = acc[i][j][q] + bt;
          t = fmaxf(t, NEG * t);
          rowdot[i][q] += t * wf;
        }
    }
#pragma unroll
    for (int i = 0; i < MI; ++i)
#pragma unroll
      for (int q = 0; q < 4; ++q) {
#pragma unroll
        for (int off = 1; off < 16; off <<= 1)
          rowdot[i][q] += __shfl_xor(rowdot[i][q], off, 16);
        if (lr == 0) dotbuf[wr * (BM / 2) + 16 * i + lk * 4 + q][wc] = rowdot[i][q];
      }
    __syncthreads();
    if (threadIdx.x < BM) {
      const float s = dotbuf[threadIdx.x][0] + dotbuf[threadIdx.x][1];
      dout[bm0 + threadIdx.x] = fmaxf(s, NEG * s);
    }
    return;
  }

#pragma unroll
  for (int j = 0; j < OJ; ++j) {
    const int o = bo0 + wc * (BO / 2) + 16 * j + lr;
    const float bt = (MODE == 1) ? betap[o] : 0.f;
#pragma unroll
    for (int i = 0; i < MI; ++i) {
      const int r0 = bm0 + wr * (BM / 2) + 16 * i + lk * 4;
#pragma unroll
      for (int q = 0; q < 4; ++q) {
        float t = acc[i][j][q];
        if (MODE == 1) { t += bt; t = fmaxf(t, NEG * t); }
        out[(size_t)(r0 + q) * ldout + o] = (_Float16)t;
      }
    }
  }
}

// ---------------- edge max, distributed: lrelu(max_k z[nbr] - z[p] + beta) ---
// idx row loaded once per TPP-group, broadcast via shfl; inner loop = packed max.
template <int O>
__global__ __launch_bounds__(256) void edge_max8(
    const _Float16* __restrict__ z, const int* __restrict__ idx,
    const float* __restrict__ betap, _Float16* __restrict__ out, int ldout) {
  constexpr int TPP = O / 8;
  constexpr int PPB = 256 / TPP;
  constexpr int NW = (K_ + TPP - 1) / TPP;
  const int t = threadIdx.x;
  const int batch = blockIdx.x & 7;
  const int chunk = blockIdx.x >> 3;
  const int p = (batch << 12) + chunk * PPB + t / TPP;
  const int lid = t % TPP;
  const int cb = lid * 8;
  const int* ip = idx + (size_t)p * K_;
  int ir[NW];
#pragma unroll
  for (int wv = 0; wv < NW; ++wv) {
    const int l = wv * TPP + lid;
    ir[wv] = (l < K_) ? ip[l] : ip[0];
  }
  const _Float16* zb = z + ((size_t)(batch << 12)) * O;

  f16x8 mx = *reinterpret_cast<const f16x8*>(zb + (size_t)__shfl(ir[0], 0, TPP) * O + cb);
#pragma unroll
  for (int k = 1; k < K_; ++k) {
    const int g = __shfl(ir[k / TPP], k % TPP, TPP);
    const f16x8 v = *reinterpret_cast<const f16x8*>(zb + (size_t)g * O + cb);
#pragma unroll
    for (int q = 0; q < 8; ++q) mx[q] = v[q] > mx[q] ? v[q] : mx[q];
  }
  const f16x8 vc = *reinterpret_cast<const f16x8*>(z + (size_t)p * O + cb);
  f16x8 vo;
#pragma unroll
  for (int q = 0; q < 8; ++q) {
    const float e = (float)mx[q] - (float)vc[q] + betap[cb + q];
    vo[q] = (_Float16)fmaxf(e, NEG * e);
  }
  *reinterpret_cast<f16x8*>(out + (size_t)p * ldout + cb) = vo;
}

// ---------------- launch -----------------------------------------------------
extern "C" void kernel_launch(void* const* d_in, const int* in_sizes, int n_in,
                              void* d_out, int out_size, void* d_ws, size_t ws_size,
                              hipStream_t stream) {
  const float* x  = (const float*)d_in[0];
  const int* idx  = (const int*)d_in[1];
  const float* w[7];
  for (int i = 0; i < 7; ++i) w[i] = (const float*)d_in[2 + i];
  const float* bn[24];
  for (int i = 0; i < 24; ++i) bn[i] = (const float*)d_in[9 + i];

  // ws map: P fp32 @0 (32KB) | Wh fp16 @32KB (~0.42MB) | z fp16 @1MB (16MB) |
  //         h512 fp16 @17MB (32MB).  h5 aliases z.
  float* P       = (float*)d_ws;
  _Float16* Wh   = (_Float16*)((char*)d_ws + (32 << 10));
  _Float16* z    = (_Float16*)((char*)d_ws + (1 << 20));
  _Float16* h512 = (_Float16*)((char*)d_ws + (17u << 20));
  _Float16* h5 = z;

  prep<<<817, 256, 0, stream>>>(
      w[1], w[2], w[3], w[4], w[5],
      bn[0], bn[1], bn[2], bn[3],   bn[4], bn[5], bn[6], bn[7],
      bn[8], bn[9], bn[10], bn[11], bn[12], bn[13], bn[14], bn[15],
      bn[16], bn[17], bn[18], bn[19], bn[20], bn[21], bn[22], bn[23],
      P, Wh);

  const float* inv1 = P + 0,    *bt1 = P + 64;
  const float* bt2 = P + 192;
  const float* bt3 = P + 384;
  const float* bt4 = P + 768;
  const float* bt5 = P + 1280;
  const float* bt6 = P + 1664;
  const _Float16* W2 = Wh + 0, *W3 = Wh + 4096, *W4 = Wh + 12288,
               *W5 = Wh + 45056, *W6 = Wh + 176128;

  // L1: edgeconv(3 -> 64)
  gemm_c3<<<M_ / 64, 256, 0, stream>>>(x, w[0], inv1, z);
  edge_max8<64><<<M_ / 32, 256, 0, stream>>>(z, idx, bt1, h512 + 0, 512);
  // L2: edgeconv(64 -> 64)
  gemm_lds<64, 64, 64, 0><<<dim3(M_ / 64, 1), 256, 0, stream>>>(h512 + 0, 512, W2, nullptr, z, 64);
  edge_max8<64><<<M_ / 32, 256, 0, stream>>>(z, idx, bt2, h512 + 64, 512);
  // L3: edgeconv(64 -> 128)
  gemm_lds<64, 128, 64, 0><<<dim3(M_ / 64, 1), 256, 0, stream>>>(h512 + 64, 512, W3, nullptr, z, 128);
  edge_max8<128><<<M_ / 16, 256, 0, stream>>>(z, idx, bt3, h512 + 128, 512);
  // L4: edgeconv(128 -> 256)
  gemm_pipe<128, 128, 128, 0><<<dim3(M_ / 128, 2), 256, 0, stream>>>(
      h512 + 128, 512, W4, nullptr, z, 256, nullptr, nullptr);
  edge_max8<256><<<M_ / 8, 256, 0, stream>>>(z, idx, bt4, h512 + 256, 512);
  // L5: pointconv(512 -> 256)
  gemm_pipe<128, 128, 512, 1><<<dim3(M_ / 128, 2), 256, 0, stream>>>(
      h512, 512, W5, bt5, h5, 256, nullptr, nullptr);
  // L6+L7: pointconv(256 -> 128) fused with final 128 -> 1 + lrelu
  gemm_pipe<128, 128, 256, 2><<<dim3(M_ / 128, 1), 256, 0, stream>>>(
      h5, 256, W6, bt6, nullptr, 0, w[6], (float*)d_out);
}

// Round 7
// 102.422 us; speedup vs baseline: 3.7094x; 1.0357x over previous
//
#include <hip/hip_runtime.h>
#include <hip/hip_bf16.h>
#include <cstdint>
#include <cstddef>

#define EPS 1e-5f
#define NEG 0.2f

static constexpr int B_ = 8, N_ = 4096, K_ = 20, M_ = B_ * N_;  // M = 32768

typedef __attribute__((ext_vector_type(8))) _Float16 f16x8;
typedef __attribute__((ext_vector_type(4))) float f32x4;

// async global->LDS, 16B per lane; LDS dest = wave-uniform base + lane*16
__device__ __forceinline__ void gload_lds16(const _Float16* g, _Float16* l) {
  __builtin_amdgcn_global_load_lds(
      (const __attribute__((address_space(1))) uint32_t*)g,
      (__attribute__((address_space(3))) uint32_t*)l, 16, 0, 0);
}

// ---------------- prep + layer-1 C=3 GEMM, one kernel ------------------------
// blocks 0..511: gemm_c3 ; 512..1327: weight fold ; 1328: BN param table
__global__ __launch_bounds__(256) void prep_c3(
    const float* __restrict__ x, const float* __restrict__ w1,
    const float* __restrict__ w2, const float* __restrict__ w3,
    const float* __restrict__ w4, const float* __restrict__ w5,
    const float* __restrict__ w6,
    const float* __restrict__ g1, const float* __restrict__ b1, const float* __restrict__ m1, const float* __restrict__ v1,
    const float* __restrict__ g2, const float* __restrict__ b2, const float* __restrict__ m2, const float* __restrict__ v2,
    const float* __restrict__ g3, const float* __restrict__ b3, const float* __restrict__ m3, const float* __restrict__ v3,
    const float* __restrict__ g4, const float* __restrict__ b4, const float* __restrict__ m4, const float* __restrict__ v4,
    const float* __restrict__ g5, const float* __restrict__ b5, const float* __restrict__ m5, const float* __restrict__ v5,
    const float* __restrict__ g6, const float* __restrict__ b6, const float* __restrict__ m6, const float* __restrict__ v6,
    float* __restrict__ P, _Float16* __restrict__ Wh, _Float16* __restrict__ z) {
  const int bid = blockIdx.x, tid = threadIdx.x;
  if (bid < 512) {
    const int o  = tid & 63;
    const int pi = tid >> 6;
    const float ww0 = w1[o * 3 + 0], ww1 = w1[o * 3 + 1], ww2 = w1[o * 3 + 2];
    const float iv = g1[o] * rsqrtf(v1[o] + EPS);
    const int pbase = bid * 64;
    const int b = pbase >> 12;
    const int nbase = pbase & (N_ - 1);
    const float* xb = x + (size_t)b * 3 * N_;
    for (int pj = pi; pj < 64; pj += 4) {
      const int n = nbase + pj;
      const float x0 = xb[n], x1v = xb[N_ + n], x2v = xb[2 * N_ + n];
      z[(size_t)(pbase + pj) * 64 + o] = (_Float16)((x0 * ww0 + x1v * ww1 + x2v * ww2) * iv);
    }
    return;
  }
  if (bid == 1328) {
    const float* G[6]  = {g1, g2, g3, g4, g5, g6};
    const float* Bb[6] = {b1, b2, b3, b4, b5, b6};
    const float* Mm[6] = {m1, m2, m3, m4, m5, m6};
    const float* Vv[6] = {v1, v2, v3, v4, v5, v6};
    const int Cs[6] = {64, 64, 128, 256, 256, 128};
    const int OI[6] = {0, 128, 256, 512, 1024, 1536};
    const int OB[6] = {64, 192, 384, 768, 1280, 1664};
    for (int l = 0; l < 6; ++l) {
      for (int c = tid; c < Cs[l]; c += 256) {
        float iv = G[l][c] * rsqrtf(Vv[l][c] + EPS);
        P[OI[l] + c] = iv;
        P[OB[l] + c] = Bb[l][c] - Mm[l][c] * iv;
      }
    }
    return;
  }
  const int fb = bid - 512;
  const float* w; const float* g; const float* v; _Float16* dst; int lc, base;
  if (fb < 16)       { w = w2; g = g2; v = v2; dst = Wh + 0;      lc = 6; base = 0;   }
  else if (fb < 48)  { w = w3; g = g3; v = v3; dst = Wh + 4096;   lc = 6; base = 16;  }
  else if (fb < 176) { w = w4; g = g4; v = v4; dst = Wh + 12288;  lc = 7; base = 48;  }
  else if (fb < 688) { w = w5; g = g5; v = v5; dst = Wh + 45056;  lc = 9; base = 176; }
  else               { w = w6; g = g6; v = v6; dst = Wh + 176128; lc = 8; base = 688; }
  const int e = (fb - base) * 256 + tid;
  const int o = e >> lc;
  dst[e] = (_Float16)(w[e] * (g[o] * rsqrtf(v[o] + EPS)));
}

// ---------------- fused edge(C=64) + GEMM ------------------------------------
// Block = 128 points of one batch (batch = bid&7 for XCD-L2 locality).
// Phase 1: W staged async; edge-max over z (ld 64) -> h512 write + LDS A
//          in MFMA fragment layout. Phase 2: GEMM -> zout.
template <int BO>
__global__ __launch_bounds__(256) void edge_gemm64(
    const _Float16* __restrict__ z, const int* __restrict__ idx,
    const float* __restrict__ betap,          // edge beta (64)
    const _Float16* __restrict__ W,           // (BO, 64) inv-folded
    _Float16* __restrict__ hout,              // h512 column base (ld 512)
    _Float16* __restrict__ zout, int ldzout) {
  constexpr int GW = BO / 8;
  constexpr int OJ = BO / 32;
  __shared__ _Float16 Asmem[128 * 64];
  __shared__ _Float16 Wsmem[BO * 64];

  const int tid = threadIdx.x, lane = tid & 63, wid = tid >> 6;
  const int batch = blockIdx.x & 7, chunk = blockIdx.x >> 3;
  const int bm0 = (batch << 12) + chunk * 128;
  const int lr = lane & 15, lk = lane >> 4;

  // stage W (fragment-contiguous groups) asynchronously
  const _Float16* Wbase = W + (size_t)lr * 64 + lk * 8;
#pragma unroll
  for (int g = wid; g < GW; g += 4) {
    const int o = g >> 1, s = g & 1;
    gload_lds16(Wbase + (size_t)16 * o * 64 + s * 32, Wsmem + g * 512);
  }

  // edge phase: 4 passes x 32 points; thread owns 8 channels of one point
  const int lid = tid & 7, cb = lid * 8;
  float bt[8];
#pragma unroll
  for (int q = 0; q < 8; ++q) bt[q] = betap[cb + q];
  const _Float16* zb = z + ((size_t)(batch << 12)) * 64;
#pragma unroll
  for (int pass = 0; pass < 4; ++pass) {
    const int pi = pass * 32 + (tid >> 3);
    const int p = bm0 + pi;
    const int* ip = idx + (size_t)p * K_;
    const int ir0 = ip[lid];
    const int ir1 = ip[8 + lid];
    const int ir2 = ip[16 + (lid & 3)];
    f16x8 mx = *reinterpret_cast<const f16x8*>(zb + (size_t)__shfl(ir0, 0, 8) * 64 + cb);
#pragma unroll
    for (int k = 1; k < K_; ++k) {
      const int g = (k < 8) ? __shfl(ir0, k, 8)
                  : (k < 16) ? __shfl(ir1, k - 8, 8)
                             : __shfl(ir2, k - 16, 8);
      const f16x8 v = *reinterpret_cast<const f16x8*>(zb + (size_t)g * 64 + cb);
#pragma unroll
      for (int q = 0; q < 8; ++q) mx[q] = v[q] > mx[q] ? v[q] : mx[q];
    }
    const f16x8 vc = *reinterpret_cast<const f16x8*>(z + (size_t)p * 64 + cb);
    f16x8 vo;
#pragma unroll
    for (int q = 0; q < 8; ++q) {
      const float e = (float)mx[q] - (float)vc[q] + bt[q];
      vo[q] = (_Float16)fmaxf(e, NEG * e);
    }
    *reinterpret_cast<f16x8*>(hout + (size_t)p * 512 + cb) = vo;
    // LDS A fragment layout: row=pi, k=cb
    const int i = pi >> 4, rr = pi & 15, s = cb >> 5, kk = (cb >> 3) & 3;
    *reinterpret_cast<f16x8*>(Asmem + (i * 2 + s) * 512 + ((kk << 4) | rr) * 8) = vo;
  }
  __syncthreads();   // waits vmcnt(0) + lgkmcnt(0): W staged, A written

  // GEMM: 4 waves (2x2), per-wave 64 x (BO/2)
  const int wr = wid >> 1, wc = wid & 1;
  f32x4 acc[4][OJ];
#pragma unroll
  for (int i = 0; i < 4; ++i)
#pragma unroll
    for (int j = 0; j < OJ; ++j) acc[i][j] = (f32x4){0.f, 0.f, 0.f, 0.f};
#pragma unroll
  for (int s = 0; s < 2; ++s) {
    f16x8 av[4], wv[OJ];
#pragma unroll
    for (int i = 0; i < 4; ++i)
      av[i] = *reinterpret_cast<const f16x8*>(Asmem + ((wr * 4 + i) * 2 + s) * 512 + lane * 8);
#pragma unroll
    for (int j = 0; j < OJ; ++j)
      wv[j] = *reinterpret_cast<const f16x8*>(Wsmem + ((wc * OJ + j) * 2 + s) * 512 + lane * 8);
#pragma unroll
    for (int i = 0; i < 4; ++i)
#pragma unroll
      for (int j = 0; j < OJ; ++j)
        acc[i][j] = __builtin_amdgcn_mfma_f32_16x16x32_f16(av[i], wv[j], acc[i][j], 0, 0, 0);
  }

#pragma unroll
  for (int j = 0; j < OJ; ++j) {
    const int o = wc * (BO / 2) + 16 * j + lr;
#pragma unroll
    for (int i = 0; i < 4; ++i) {
      const int r0 = bm0 + wr * 64 + 16 * i + lk * 4;
#pragma unroll
      for (int q = 0; q < 4; ++q)
        zout[(size_t)(r0 + q) * ldzout + o] = (_Float16)acc[i][j][q];
    }
  }
}

// ---------------- fp16 MFMA GEMM, 4-buffer counted-vmcnt pipeline ------------
// MODE 0: out=acc  MODE 1: lrelu(acc+beta)  MODE 2: MODE1 then fused dot w7
template <int BM, int BO, int C, int MODE>
__global__ __launch_bounds__(256) void gemm_pipe(
    const _Float16* __restrict__ A, int lda,
    const _Float16* __restrict__ W,
    const float* __restrict__ betap,
    _Float16* __restrict__ out, int ldout,
    const float* __restrict__ w7, float* __restrict__ dout) {
  constexpr int NK = C / 32;
  constexpr int GA = BM / 16;
  constexpr int GW = BO / 16;
  constexpr int GT = GA + GW;
  constexpr int GP = GT / 4;
  constexpr int SB = (BM + BO) * 32;
  constexpr int MI = BM / 32, OJ = BO / 32;
  __shared__ _Float16 lds[4 * SB];

  const int lane = threadIdx.x & 63;
  const int wid  = threadIdx.x >> 6;
  const int wr = wid >> 1, wc = wid & 1;
  const int bm0 = blockIdx.x * BM;
  const int bo0 = blockIdx.y * BO;
  const int lr = lane & 15, lk = lane >> 4;

  const _Float16* Abase = A + (size_t)(bm0 + lr) * lda + lk * 8;
  const _Float16* Wbase = W + (size_t)(bo0 + lr) * C + lk * 8;

  f32x4 acc[MI][OJ];
#pragma unroll
  for (int i = 0; i < MI; ++i)
#pragma unroll
    for (int j = 0; j < OJ; ++j) acc[i][j] = (f32x4){0.f, 0.f, 0.f, 0.f};

  auto stage = [&](int buf, int k0) {
    _Float16* dst = &lds[buf * SB];
#pragma unroll
    for (int q = 0; q < GP; ++q) {
      const int g = wid * GP + q;
      const _Float16* src = (g < GA)
          ? Abase + (size_t)16 * g * lda + k0
          : Wbase + (size_t)16 * (g - GA) * C + k0;
      gload_lds16(src, dst + g * 512);
    }
  };

  auto compute = [&](int buf) {
    const _Float16* Ab = &lds[buf * SB];
    const _Float16* Wb = &lds[buf * SB + GA * 512];
    f16x8 av[MI], wv[OJ];
#pragma unroll
    for (int i = 0; i < MI; ++i)
      av[i] = *reinterpret_cast<const f16x8*>(Ab + (wr * MI + i) * 512 + lane * 8);
#pragma unroll
    for (int j = 0; j < OJ; ++j)
      wv[j] = *reinterpret_cast<const f16x8*>(Wb + (wc * OJ + j) * 512 + lane * 8);
#pragma unroll
    for (int i = 0; i < MI; ++i)
#pragma unroll
      for (int j = 0; j < OJ; ++j)
        acc[i][j] = __builtin_amdgcn_mfma_f32_16x16x32_f16(av[i], wv[j], acc[i][j], 0, 0, 0);
  };

  stage(0, 0);
  stage(1, 32);
#pragma unroll
  for (int t = 0; t < NK; ++t) {
    if (t + 2 < NK) {
      stage((t + 2) & 3, (t + 2) * 32);
      if constexpr (GP == 4) asm volatile("s_waitcnt vmcnt(8)" ::: "memory");
      else                   asm volatile("s_waitcnt vmcnt(6)" ::: "memory");
    } else if (t + 1 < NK) {
      if constexpr (GP == 4) asm volatile("s_waitcnt vmcnt(4)" ::: "memory");
      else                   asm volatile("s_waitcnt vmcnt(3)" ::: "memory");
    } else {
      asm volatile("s_waitcnt vmcnt(0)" ::: "memory");
    }
    __builtin_amdgcn_s_barrier();
    compute(t & 3);
  }

  if constexpr (MODE == 2) {
    __shared__ float dotbuf[BM][2];
    float rowdot[MI][4];
#pragma unroll
    for (int i = 0; i < MI; ++i)
#pragma unroll
      for (int q = 0; q < 4; ++q) rowdot[i][q] = 0.f;
#pragma unroll
    for (int j = 0; j < OJ; ++j) {
      const int o = wc * (BO / 2) + 16 * j + lr;
      const float bt = betap[o];
      const float wf = w7[o];
#pragma unroll
      for (int i = 0; i < MI; ++i)
#pragma unroll
        for (int q = 0; q < 4; ++q) {
          float t = acc[i][j][q] + bt;
          t = fmaxf(t, NEG * t);
          rowdot[i][q] += t * wf;
        }
    }
#pragma unroll
    for (int i = 0; i < MI; ++i)
#pragma unroll
      for (int q = 0; q < 4; ++q) {
#pragma unroll
        for (int off = 1; off < 16; off <<= 1)
          rowdot[i][q] += __shfl_xor(rowdot[i][q], off, 16);
        if (lr == 0) dotbuf[wr * (BM / 2) + 16 * i + lk * 4 + q][wc] = rowdot[i][q];
      }
    __syncthreads();
    if (threadIdx.x < BM) {
      const float s = dotbuf[threadIdx.x][0] + dotbuf[threadIdx.x][1];
      dout[bm0 + threadIdx.x] = fmaxf(s, NEG * s);
    }
    return;
  }

#pragma unroll
  for (int j = 0; j < OJ; ++j) {
    const int o = bo0 + wc * (BO / 2) + 16 * j + lr;
    const float bt = (MODE == 1) ? betap[o] : 0.f;
#pragma unroll
    for (int i = 0; i < MI; ++i) {
      const int r0 = bm0 + wr * (BM / 2) + 16 * i + lk * 4;
#pragma unroll
      for (int q = 0; q < 4; ++q) {
        float t = acc[i][j][q];
        if (MODE == 1) { t += bt; t = fmaxf(t, NEG * t); }
        out[(size_t)(r0 + q) * ldout + o] = (_Float16)t;
      }
    }
  }
}

// ---------------- edge max, standalone (O=128/256) ---------------------------
template <int O>
__global__ __launch_bounds__(256) void edge_max8(
    const _Float16* __restrict__ z, const int* __restrict__ idx,
    const float* __restrict__ betap, _Float16* __restrict__ out, int ldout) {
  constexpr int TPP = O / 8;
  constexpr int PPB = 256 / TPP;
  constexpr int NW = (K_ + TPP - 1) / TPP;
  const int t = threadIdx.x;
  const int batch = blockIdx.x & 7;
  const int chunk = blockIdx.x >> 3;
  const int p = (batch << 12) + chunk * PPB + t / TPP;
  const int lid = t % TPP;
  const int cb = lid * 8;
  const int* ip = idx + (size_t)p * K_;
  int ir[NW];
#pragma unroll
  for (int wv = 0; wv < NW; ++wv) {
    const int l = wv * TPP + lid;
    ir[wv] = (l < K_) ? ip[l] : ip[0];
  }
  const _Float16* zb = z + ((size_t)(batch << 12)) * O;

  f16x8 mx = *reinterpret_cast<const f16x8*>(zb + (size_t)__shfl(ir[0], 0, TPP) * O + cb);
#pragma unroll
  for (int k = 1; k < K_; ++k) {
    const int g = __shfl(ir[k / TPP], k % TPP, TPP);
    const f16x8 v = *reinterpret_cast<const f16x8*>(zb + (size_t)g * O + cb);
#pragma unroll
    for (int q = 0; q < 8; ++q) mx[q] = v[q] > mx[q] ? v[q] : mx[q];
  }
  const f16x8 vc = *reinterpret_cast<const f16x8*>(z + (size_t)p * O + cb);
  f16x8 vo;
#pragma unroll
  for (int q = 0; q < 8; ++q) {
    const float e = (float)mx[q] - (float)vc[q] + betap[cb + q];
    vo[q] = (_Float16)fmaxf(e, NEG * e);
  }
  *reinterpret_cast<f16x8*>(out + (size_t)p * ldout + cb) = vo;
}

// ---------------- launch -----------------------------------------------------
extern "C" void kernel_launch(void* const* d_in, const int* in_sizes, int n_in,
                              void* d_out, int out_size, void* d_ws, size_t ws_size,
                              hipStream_t stream) {
  const float* x  = (const float*)d_in[0];
  const int* idx  = (const int*)d_in[1];
  const float* w[7];
  for (int i = 0; i < 7; ++i) w[i] = (const float*)d_in[2 + i];
  const float* bn[24];
  for (int i = 0; i < 24; ++i) bn[i] = (const float*)d_in[9 + i];

  // ws: P@0 (32KB) | Wh@32KB (~0.42MB) | z_a@1MB (16MB) | h512@17MB (32MB) | z_b@49MB (16MB)
  float* P       = (float*)d_ws;
  _Float16* Wh   = (_Float16*)((char*)d_ws + (32 << 10));
  _Float16* z_a  = (_Float16*)((char*)d_ws + (1u << 20));
  _Float16* h512 = (_Float16*)((char*)d_ws + (17u << 20));
  _Float16* z_b  = (_Float16*)((char*)d_ws + (49u << 20));

  prep_c3<<<1329, 256, 0, stream>>>(
      x, w[0], w[1], w[2], w[3], w[4], w[5],
      bn[0], bn[1], bn[2], bn[3],   bn[4], bn[5], bn[6], bn[7],
      bn[8], bn[9], bn[10], bn[11], bn[12], bn[13], bn[14], bn[15],
      bn[16], bn[17], bn[18], bn[19], bn[20], bn[21], bn[22], bn[23],
      P, Wh, z_a);

  const float* bt1 = P + 64;
  const float* bt2 = P + 192;
  const float* bt3 = P + 384;
  const float* bt4 = P + 768;
  const float* bt5 = P + 1280;
  const float* bt6 = P + 1664;
  const _Float16* W2 = Wh + 0, *W3 = Wh + 4096, *W4 = Wh + 12288,
               *W5 = Wh + 45056, *W6 = Wh + 176128;

  // L1 edge + L2 GEMM fused: z1 -> (x1 -> h512+0, z2 -> z_b ld 64)
  edge_gemm64<64><<<M_ / 128, 256, 0, stream>>>(z_a, idx, bt1, W2, h512 + 0, z_b, 64);
  // L2 edge + L3 GEMM fused: z2 -> (x2 -> h512+64, z3 -> z_a ld 128)
  edge_gemm64<128><<<M_ / 128, 256, 0, stream>>>(z_b, idx, bt2, W3, h512 + 64, z_a, 128);
  // L3 edge: z3 -> x3 (h512+128)
  edge_max8<128><<<M_ / 16, 256, 0, stream>>>(z_a, idx, bt3, h512 + 128, 512);
  // L4 GEMM: x3 -> z4 (z_b ld 256)
  gemm_pipe<128, 128, 128, 0><<<dim3(M_ / 128, 2), 256, 0, stream>>>(
      h512 + 128, 512, W4, nullptr, z_b, 256, nullptr, nullptr);
  // L4 edge: z4 -> x4 (h512+256)
  edge_max8<256><<<M_ / 8, 256, 0, stream>>>(z_b, idx, bt4, h512 + 256, 512);
  // L5: pointconv(512 -> 256) -> z_a ld 256
  gemm_pipe<128, 128, 512, 1><<<dim3(M_ / 128, 2), 256, 0, stream>>>(
      h512, 512, W5, bt5, z_a, 256, nullptr, nullptr);
  // L6+L7: pointconv(256 -> 128) fused with final 128 -> 1 + lrelu
  gemm_pipe<64, 128, 256, 2><<<dim3(M_ / 64, 1), 256, 0, stream>>>(
      z_a, 256, W6, bt6, nullptr, 0, w[6], (float*)d_out);
}